// Round 6
// baseline (832.067 us; speedup 1.0000x reference)
//
#include <hip/hip_runtime.h>
#include <hip/hip_cooperative_groups.h>
#include <math.h>

namespace cg = cooperative_groups;

#define BB 16
#define QQ 1024
#define TT 1024
#define DD 256
#define EPS 0.1f
#define SINK_ITERS 5
// FC replaces 2*max(cost); it cancels algebraically (filtered col: v_t = FC - lse;
// consumers subtract it back). Needs FC >> max(cost)+2; max cost ~40.
#define FCONST 128.0f
#define K2 14.426950408889634f        // (1/eps) * log2(e)
#define EPSLN2 0.069314718055994531f  // eps * ln(2)

typedef _Float16 f16;
typedef _Float16 f16x4 __attribute__((ext_vector_type(4)));
typedef _Float16 f16x8 __attribute__((ext_vector_type(8)));
typedef float f32x4 __attribute__((ext_vector_type(4)));

__device__ __forceinline__ float fast_exp2(float x) {
#if __has_builtin(__builtin_amdgcn_exp2f)
  return __builtin_amdgcn_exp2f(x);
#else
  return exp2f(x);
#endif
}
__device__ __forceinline__ float fast_log2(float x) {
#if __has_builtin(__builtin_amdgcn_logf)
  return __builtin_amdgcn_logf(x);
#else
  return log2f(x);
#endif
}

// ---------------- cvt: fp32 -> (hi,lo) f16 split + fused row norms ----------------
__global__ __launch_bounds__(256) void cvt_kernel(
    const float* __restrict__ preds, const float* __restrict__ targets,
    f16* __restrict__ Ahi, f16* __restrict__ Alo,
    f16* __restrict__ Bhi, f16* __restrict__ Blo,
    float* __restrict__ x2, float* __restrict__ y2)
{
  int w = threadIdx.x >> 6, l = threadIdx.x & 63;
  int row = blockIdx.x * 4 + w;
  const float* src; f16 *hi, *lo; float* nrm;
  if (row < BB*QQ) {
    src = preds + (size_t)row * DD;
    hi = Ahi + (size_t)row * DD; lo = Alo + (size_t)row * DD; nrm = x2 + row;
  } else {
    int r = row - BB*QQ;
    src = targets + (size_t)r * DD;
    hi = Bhi + (size_t)r * DD; lo = Blo + (size_t)r * DD; nrm = y2 + r;
  }
  float4 v = ((const float4*)src)[l];
  f16x4 h, lw;
  h.x = (f16)v.x; h.y = (f16)v.y; h.z = (f16)v.z; h.w = (f16)v.w;
  lw.x = (f16)(v.x - (float)h.x); lw.y = (f16)(v.y - (float)h.y);
  lw.z = (f16)(v.z - (float)h.z); lw.w = (f16)(v.w - (float)h.w);
  *(f16x4*)(hi + l*4) = h;
  *(f16x4*)(lo + l*4) = lw;
  float s = v.x*v.x + v.y*v.y + v.z*v.z + v.w*v.w;
  #pragma unroll
  for (int o = 32; o; o >>= 1) s += __shfl_down(s, o, 64);
  if (l == 0) *nrm = s;
}

// ---------------- MFMA cost kernel: 128x128 tile, 64x64/wave, 16x16x32 f16 ----------------
__global__ __launch_bounds__(256) void cost_mfma_kernel(
    const f16* __restrict__ Ahi, const f16* __restrict__ Alo,
    const f16* __restrict__ Bhi, const f16* __restrict__ Blo,
    const float* __restrict__ x2, const float* __restrict__ y2,
    const float* __restrict__ filter,
    float* __restrict__ cost, float* __restrict__ costT, int useT)
{
  __shared__ f16 sA[2][128*32];
  __shared__ f16 sB[2][128*32];
  int b = blockIdx.z;
  int q0 = blockIdx.y * 128, t0 = blockIdx.x * 128;
  int tid = threadIdx.x, w = tid >> 6, l = tid & 63;
  int rq = (w >> 1) * 64, rt = (w & 1) * 64;
  int fr = l & 15, fg = l >> 4;
  const f16* pA[2] = { Ahi + ((size_t)b*QQ + q0) * DD, Alo + ((size_t)b*QQ + q0) * DD };
  const f16* pB[2] = { Bhi + ((size_t)b*TT + t0) * DD, Blo + ((size_t)b*TT + t0) * DD };
  f32x4 acc[4][4] = {};
  for (int k0 = 0; k0 < DD; k0 += 32) {
    __syncthreads();
#if __has_builtin(__builtin_amdgcn_global_load_lds)
    #pragma unroll
    for (int j = 0; j < 2; ++j) {
      int chunk = w*128 + j*64 + l;
      int row = chunk >> 2, kc = chunk & 3;
      size_t go = (size_t)row * DD + k0 + kc*8;
      int lb = (w*128 + j*64) * 8;
      #pragma unroll
      for (int h = 0; h < 2; ++h) {
        __builtin_amdgcn_global_load_lds(
            (const __attribute__((address_space(1))) void*)(pA[h] + go),
            (__attribute__((address_space(3))) void*)&sA[h][lb], 16, 0, 0);
        __builtin_amdgcn_global_load_lds(
            (const __attribute__((address_space(1))) void*)(pB[h] + go),
            (__attribute__((address_space(3))) void*)&sB[h][lb], 16, 0, 0);
      }
    }
#else
    #pragma unroll
    for (int j = 0; j < 2; ++j) {
      int chunk = w*128 + j*64 + l;
      int row = chunk >> 2, kc = chunk & 3;
      size_t go = (size_t)row * DD + k0 + kc*8;
      #pragma unroll
      for (int h = 0; h < 2; ++h) {
        *(f16x8*)&sA[h][chunk*8] = *(const f16x8*)(pA[h] + go);
        *(f16x8*)&sB[h][chunk*8] = *(const f16x8*)(pB[h] + go);
      }
    }
#endif
    __syncthreads();
    f16x8 ah[4], al[4], bh[4], bl[4];
    #pragma unroll
    for (int f = 0; f < 4; ++f) {
      int ao = (rq + f*16 + fr)*32 + fg*8;
      ah[f] = *(const f16x8*)&sA[0][ao];
      al[f] = *(const f16x8*)&sA[1][ao];
      int bo = (rt + f*16 + fr)*32 + fg*8;
      bh[f] = *(const f16x8*)&sB[0][bo];
      bl[f] = *(const f16x8*)&sB[1][bo];
    }
    #pragma unroll
    for (int fm = 0; fm < 4; ++fm)
      #pragma unroll
      for (int fn = 0; fn < 4; ++fn) {
        acc[fm][fn] = __builtin_amdgcn_mfma_f32_16x16x32_f16(ah[fm], bh[fn], acc[fm][fn], 0, 0, 0);
        acc[fm][fn] = __builtin_amdgcn_mfma_f32_16x16x32_f16(ah[fm], bl[fn], acc[fm][fn], 0, 0, 0);
        acc[fm][fn] = __builtin_amdgcn_mfma_f32_16x16x32_f16(al[fm], bh[fn], acc[fm][fn], 0, 0, 0);
      }
  }
  float xv[16];
  #pragma unroll
  for (int fm = 0; fm < 4; ++fm)
    #pragma unroll
    for (int r = 0; r < 4; ++r)
      xv[fm*4+r] = x2[(size_t)b*QQ + q0 + rq + fm*16 + fg*4 + r];
  float yv[4], fv[4];
  #pragma unroll
  for (int fn = 0; fn < 4; ++fn) {
    int t = t0 + rt + fn*16 + fr;
    yv[fn] = y2[(size_t)b*TT + t];
    fv[fn] = filter[(size_t)b*TT + t];
  }
  #pragma unroll
  for (int fm = 0; fm < 4; ++fm) {
    #pragma unroll
    for (int fn = 0; fn < 4; ++fn) {
      int t = t0 + rt + fn*16 + fr;
      float cvr[4];
      #pragma unroll
      for (int r = 0; r < 4; ++r) {
        float c2 = xv[fm*4+r] + yv[fn] - 2.0f*acc[fm][fn][r];
        float c = sqrtf(fmaxf(c2, 0.f));
        if (fv[fn] <= 0.f) c = FCONST;
        cvr[r] = c;
        int q = q0 + rq + fm*16 + fg*4 + r;
        cost[((size_t)b*QQ + q)*TT + t] = c;
      }
      // filtered columns of costT are never read by v-phase -> skip the write
      if (useT && fv[fn] > 0.f) {
        float* dst = costT + ((size_t)b*TT + t)*QQ + q0 + rq + fm*16 + fg*4;
        *(float4*)dst = make_float4(cvr[0], cvr[1], cvr[2], cvr[3]);
      }
    }
  }
}

// ---------------- fp32 fallback ----------------
__global__ __launch_bounds__(64) void norms_kernel(
    const float* __restrict__ preds, const float* __restrict__ targets,
    float* __restrict__ x2, float* __restrict__ y2)
{
  int row = blockIdx.x;
  const float* src; float* dst;
  if (row < BB*QQ) { src = preds + (size_t)row * DD; dst = x2 + row; }
  else { int r = row - BB*QQ; src = targets + (size_t)r * DD; dst = y2 + r; }
  float4 v = ((const float4*)src)[threadIdx.x];
  float s = v.x*v.x + v.y*v.y + v.z*v.z + v.w*v.w;
  #pragma unroll
  for (int o = 32; o; o >>= 1) s += __shfl_down(s, o, 64);
  if (threadIdx.x == 0) *dst = s;
}

#define LDSTR 132
__global__ __launch_bounds__(256) void cost_fp32_kernel(
    const float* __restrict__ preds, const float* __restrict__ targets,
    const float* __restrict__ x2, const float* __restrict__ y2,
    const float* __restrict__ filter,
    float* __restrict__ cost, float* __restrict__ costT, int useT)
{
  __shared__ float As[16*LDSTR];
  __shared__ float Bs[16*LDSTR];
  int b  = blockIdx.z;
  int q0 = blockIdx.y * 128;
  int t0 = blockIdx.x * 128;
  const float* Ab = preds   + ((size_t)b*QQ + q0) * DD;
  const float* Bb = targets + ((size_t)b*TT + t0) * DD;
  int tid = threadIdx.x;
  int srow = tid >> 2, sq = (tid & 3) << 2;
  int w = tid >> 6, l = tid & 63;
  int rq = ((w >> 1) << 6) + ((l >> 3) << 3);
  int rt = ((w & 1) << 6) + ((l & 7) << 3);
  float acc[8][8] = {};
  for (int k0 = 0; k0 < DD; k0 += 16) {
    float4 a0 = *(const float4*)(Ab + (size_t)srow*DD + k0 + sq);
    float4 a1 = *(const float4*)(Ab + (size_t)(srow+64)*DD + k0 + sq);
    float4 b0 = *(const float4*)(Bb + (size_t)srow*DD + k0 + sq);
    float4 b1 = *(const float4*)(Bb + (size_t)(srow+64)*DD + k0 + sq);
    __syncthreads();
    As[(sq+0)*LDSTR + srow] = a0.x; As[(sq+1)*LDSTR + srow] = a0.y;
    As[(sq+2)*LDSTR + srow] = a0.z; As[(sq+3)*LDSTR + srow] = a0.w;
    As[(sq+0)*LDSTR + srow+64] = a1.x; As[(sq+1)*LDSTR + srow+64] = a1.y;
    As[(sq+2)*LDSTR + srow+64] = a1.z; As[(sq+3)*LDSTR + srow+64] = a1.w;
    Bs[(sq+0)*LDSTR + srow] = b0.x; Bs[(sq+1)*LDSTR + srow] = b0.y;
    Bs[(sq+2)*LDSTR + srow] = b0.z; Bs[(sq+3)*LDSTR + srow] = b0.w;
    Bs[(sq+0)*LDSTR + srow+64] = b1.x; Bs[(sq+1)*LDSTR + srow+64] = b1.y;
    Bs[(sq+2)*LDSTR + srow+64] = b1.z; Bs[(sq+3)*LDSTR + srow+64] = b1.w;
    __syncthreads();
    #pragma unroll
    for (int k = 0; k < 16; ++k) {
      float4 af0 = *(const float4*)&As[k*LDSTR + rq];
      float4 af1 = *(const float4*)&As[k*LDSTR + rq + 4];
      float4 bf0 = *(const float4*)&Bs[k*LDSTR + rt];
      float4 bf1 = *(const float4*)&Bs[k*LDSTR + rt + 4];
      float aa[8] = {af0.x,af0.y,af0.z,af0.w,af1.x,af1.y,af1.z,af1.w};
      float bb[8] = {bf0.x,bf0.y,bf0.z,bf0.w,bf1.x,bf1.y,bf1.z,bf1.w};
      #pragma unroll
      for (int i = 0; i < 8; ++i)
        #pragma unroll
        for (int j = 0; j < 8; ++j)
          acc[i][j] = fmaf(aa[i], bb[j], acc[i][j]);
    }
  }
  float xq[8], yt[8], fvv[8];
  #pragma unroll
  for (int i = 0; i < 8; ++i) xq[i] = x2[(size_t)b*QQ + q0 + rq + i];
  #pragma unroll
  for (int j = 0; j < 8; ++j) {
    yt[j] = y2[(size_t)b*TT + t0 + rt + j];
    fvv[j] = filter[(size_t)b*TT + t0 + rt + j];
  }
  float cv[8][8];
  #pragma unroll
  for (int i = 0; i < 8; ++i)
    #pragma unroll
    for (int j = 0; j < 8; ++j) {
      float c2 = xq[i] + yt[j] - 2.f*acc[i][j];
      float c = sqrtf(fmaxf(c2, 0.f));
      if (fvv[j] <= 0.f) c = FCONST;
      cv[i][j] = c;
    }
  #pragma unroll
  for (int i = 0; i < 8; ++i) {
    float* dst = cost + ((size_t)b*QQ + q0 + rq + i) * TT + t0 + rt;
    *(float4*)dst       = make_float4(cv[i][0], cv[i][1], cv[i][2], cv[i][3]);
    *(float4*)(dst + 4) = make_float4(cv[i][4], cv[i][5], cv[i][6], cv[i][7]);
  }
  if (useT) {
    #pragma unroll
    for (int j = 0; j < 8; ++j) {
      if (fvv[j] <= 0.f) continue;
      float* dst = costT + ((size_t)b*TT + t0 + rt + j) * QQ + q0 + rq;
      *(float4*)dst       = make_float4(cv[0][j], cv[1][j], cv[2][j], cv[3][j]);
      *(float4*)(dst + 4) = make_float4(cv[4][j], cv[5][j], cv[6][j], cv[7][j]);
    }
  }
}

// ---------------- wave reductions ----------------
__device__ __forceinline__ float wave_max64(float v) {
  #pragma unroll
  for (int o = 1; o < 64; o <<= 1) v = fmaxf(v, __shfl_xor(v, o, 64));
  return v;
}
__device__ __forceinline__ float wave_sum64(float v) {
  #pragma unroll
  for (int o = 1; o < 64; o <<= 1) v += __shfl_xor(v, o, 64);
  return v;
}

// ---------------- device bodies shared by fused + fallback paths ----------------
__device__ __forceinline__ void u_body(int row, int l, bool it0,
    const float* __restrict__ cost, const float* __restrict__ v, float* __restrict__ u)
{
  int b = row >> 10;
  const float4* c0 = (const float4*)(cost + (size_t)row * TT);
  const float4* c1 = c0 + TT/4;
  const float4* vb = (const float4*)(v + (size_t)b * TT);
  float s0[16], s1[16], m0 = -3.0e38f, m1 = -3.0e38f;
  #pragma unroll
  for (int i = 0; i < 4; ++i) {
    float4 v4;
    if (it0) v4 = make_float4(0.f, 0.f, 0.f, 0.f);
    else     v4 = vb[l + (i << 6)];
    float4 a4 = c0[l + (i << 6)];
    float4 b4 = c1[l + (i << 6)];
    s0[4*i+0] = (v4.x - a4.x) * K2; s0[4*i+1] = (v4.y - a4.y) * K2;
    s0[4*i+2] = (v4.z - a4.z) * K2; s0[4*i+3] = (v4.w - a4.w) * K2;
    s1[4*i+0] = (v4.x - b4.x) * K2; s1[4*i+1] = (v4.y - b4.y) * K2;
    s1[4*i+2] = (v4.z - b4.z) * K2; s1[4*i+3] = (v4.w - b4.w) * K2;
    m0 = fmaxf(m0, fmaxf(fmaxf(s0[4*i+0], s0[4*i+1]), fmaxf(s0[4*i+2], s0[4*i+3])));
    m1 = fmaxf(m1, fmaxf(fmaxf(s1[4*i+0], s1[4*i+1]), fmaxf(s1[4*i+2], s1[4*i+3])));
  }
  m0 = wave_max64(m0); m1 = wave_max64(m1);
  float q0 = 0.f, q1 = 0.f;
  #pragma unroll
  for (int i = 0; i < 16; ++i) { q0 += fast_exp2(s0[i] - m0); q1 += fast_exp2(s1[i] - m1); }
  q0 = wave_sum64(q0); q1 = wave_sum64(q1);
  if (l == 0) {
    u[row]   = -EPSLN2 * (m0 + fast_log2(q0));
    u[row+1] = -EPSLN2 * (m1 + fast_log2(q1));
  }
}

__device__ __forceinline__ void v_body(int row, int l,
    const float* __restrict__ cost, const float* __restrict__ costT, int useT,
    const float* __restrict__ filter, const float* __restrict__ u, float* __restrict__ v)
{
  int b = row >> 10, t = row & 1023;
  const float4* ub = (const float4*)(u + (size_t)b * QQ);
  bool f0 = (filter[row]   <= 0.f);
  bool f1 = (filter[row+1] <= 0.f);
  float4 uw[4];
  #pragma unroll
  for (int i = 0; i < 4; ++i) uw[i] = ub[l + (i << 6)];
  float s0[16], s1[16], m0 = -3.0e38f, m1 = -3.0e38f;
  if (f0) {
    #pragma unroll
    for (int i = 0; i < 4; ++i) {
      s0[4*i+0] = (uw[i].x - FCONST) * K2; s0[4*i+1] = (uw[i].y - FCONST) * K2;
      s0[4*i+2] = (uw[i].z - FCONST) * K2; s0[4*i+3] = (uw[i].w - FCONST) * K2;
    }
  } else if (useT) {
    const float4* cr = (const float4*)(costT + (size_t)row * QQ);
    #pragma unroll
    for (int i = 0; i < 4; ++i) {
      float4 c4 = cr[l + (i << 6)];
      s0[4*i+0] = (uw[i].x - c4.x) * K2; s0[4*i+1] = (uw[i].y - c4.y) * K2;
      s0[4*i+2] = (uw[i].z - c4.z) * K2; s0[4*i+3] = (uw[i].w - c4.w) * K2;
    }
  } else {
    const float* cr = cost + (size_t)b*QQ*TT + t;
    #pragma unroll
    for (int i = 0; i < 4; ++i) {
      int q = (l + (i << 6)) << 2;
      s0[4*i+0] = (uw[i].x - cr[(size_t)(q+0)*TT]) * K2;
      s0[4*i+1] = (uw[i].y - cr[(size_t)(q+1)*TT]) * K2;
      s0[4*i+2] = (uw[i].z - cr[(size_t)(q+2)*TT]) * K2;
      s0[4*i+3] = (uw[i].w - cr[(size_t)(q+3)*TT]) * K2;
    }
  }
  if (f1) {
    #pragma unroll
    for (int i = 0; i < 4; ++i) {
      s1[4*i+0] = (uw[i].x - FCONST) * K2; s1[4*i+1] = (uw[i].y - FCONST) * K2;
      s1[4*i+2] = (uw[i].z - FCONST) * K2; s1[4*i+3] = (uw[i].w - FCONST) * K2;
    }
  } else if (useT) {
    const float4* cr = (const float4*)(costT + (size_t)(row+1) * QQ);
    #pragma unroll
    for (int i = 0; i < 4; ++i) {
      float4 c4 = cr[l + (i << 6)];
      s1[4*i+0] = (uw[i].x - c4.x) * K2; s1[4*i+1] = (uw[i].y - c4.y) * K2;
      s1[4*i+2] = (uw[i].z - c4.z) * K2; s1[4*i+3] = (uw[i].w - c4.w) * K2;
    }
  } else {
    const float* cr = cost + (size_t)b*QQ*TT + t + 1;
    #pragma unroll
    for (int i = 0; i < 4; ++i) {
      int q = (l + (i << 6)) << 2;
      s1[4*i+0] = (uw[i].x - cr[(size_t)(q+0)*TT]) * K2;
      s1[4*i+1] = (uw[i].y - cr[(size_t)(q+1)*TT]) * K2;
      s1[4*i+2] = (uw[i].z - cr[(size_t)(q+2)*TT]) * K2;
      s1[4*i+3] = (uw[i].w - cr[(size_t)(q+3)*TT]) * K2;
    }
  }
  #pragma unroll
  for (int i = 0; i < 16; ++i) { m0 = fmaxf(m0, s0[i]); m1 = fmaxf(m1, s1[i]); }
  m0 = wave_max64(m0); m1 = wave_max64(m1);
  float q0 = 0.f, q1 = 0.f;
  #pragma unroll
  for (int i = 0; i < 16; ++i) { q0 += fast_exp2(s0[i] - m0); q1 += fast_exp2(s1[i] - m1); }
  q0 = wave_sum64(q0); q1 = wave_sum64(q1);
  if (l == 0) {
    v[row]   = -EPSLN2 * (m0 + fast_log2(q0));
    v[row+1] = -EPSLN2 * (m1 + fast_log2(q1));
  }
}

__device__ __forceinline__ void p_body(int row, int l,
    float* __restrict__ P, const float* __restrict__ u, const float* __restrict__ v,
    float* __restrict__ idxOut)
{
  int b = row >> 10;
  float4* c0 = (float4*)(P + (size_t)row * TT);
  float4* c1 = c0 + TT/4;
  const float4* vb = (const float4*)(v + (size_t)b * TT);
  float u0 = u[row], u1 = u[row+1];
  float bp0 = -1.f, bp1 = -1.f; int bt0 = 0, bt1 = 0;
  #pragma unroll
  for (int i = 0; i < 4; ++i) {
    float4 v4 = vb[l + (i << 6)];
    float4 a4 = c0[l + (i << 6)];
    float4 b4 = c1[l + (i << 6)];
    int t0 = (l + (i << 6)) << 2;
    float4 p0, p1;
    p0.x = fast_exp2((u0 + v4.x - a4.x) * K2);
    p0.y = fast_exp2((u0 + v4.y - a4.y) * K2);
    p0.z = fast_exp2((u0 + v4.z - a4.z) * K2);
    p0.w = fast_exp2((u0 + v4.w - a4.w) * K2);
    p1.x = fast_exp2((u1 + v4.x - b4.x) * K2);
    p1.y = fast_exp2((u1 + v4.y - b4.y) * K2);
    p1.z = fast_exp2((u1 + v4.z - b4.z) * K2);
    p1.w = fast_exp2((u1 + v4.w - b4.w) * K2);
    if (p0.x > bp0) { bp0 = p0.x; bt0 = t0 + 0; }
    if (p0.y > bp0) { bp0 = p0.y; bt0 = t0 + 1; }
    if (p0.z > bp0) { bp0 = p0.z; bt0 = t0 + 2; }
    if (p0.w > bp0) { bp0 = p0.w; bt0 = t0 + 3; }
    if (p1.x > bp1) { bp1 = p1.x; bt1 = t0 + 0; }
    if (p1.y > bp1) { bp1 = p1.y; bt1 = t0 + 1; }
    if (p1.z > bp1) { bp1 = p1.z; bt1 = t0 + 2; }
    if (p1.w > bp1) { bp1 = p1.w; bt1 = t0 + 3; }
    c0[l + (i << 6)] = p0;
    c1[l + (i << 6)] = p1;
  }
  #pragma unroll
  for (int o = 1; o < 64; o <<= 1) {
    float op = __shfl_xor(bp0, o, 64);
    int   ot = __shfl_xor(bt0, o, 64);
    if (op > bp0 || (op == bp0 && ot < bt0)) { bp0 = op; bt0 = ot; }
    op = __shfl_xor(bp1, o, 64);
    ot = __shfl_xor(bt1, o, 64);
    if (op > bp1 || (op == bp1 && ot < bt1)) { bp1 = op; bt1 = ot; }
  }
  if (l == 0) { idxOut[row] = (float)bt0; idxOut[row+1] = (float)bt1; }
}

// ---------------- fused cooperative sweep: 5x(u,v) + p in ONE launch ----------------
// __launch_bounds__(256,4): VGPR<=128, LDS=0 -> 4 blocks/CU guaranteed -> grid 1024 co-resident.
__global__ __launch_bounds__(256, 4) void sweep_kernel(
    float* __restrict__ P, const float* __restrict__ costT, int useT,
    const float* __restrict__ filter, float* __restrict__ u, float* __restrict__ v,
    float* __restrict__ idxOut, int G)
{
  cg::grid_group grid = cg::this_grid();
  const int w = threadIdx.x >> 6, l = threadIdx.x & 63;
  for (int it = 0; it < SINK_ITERS; ++it) {
    const bool it0 = (it == 0);       // v not yet written: treat as 0
    for (int row = blockIdx.x*8 + w*2; row < BB*QQ; row += G*8)
      u_body(row, l, it0, P, v, u);
    grid.sync();
    for (int row = blockIdx.x*8 + w*2; row < BB*TT; row += G*8)
      v_body(row, l, P, costT, useT, filter, u, v);
    grid.sync();
  }
  for (int row = blockIdx.x*8 + w*2; row < BB*QQ; row += G*8)
    p_body(row, l, P, u, v, idxOut);
}

// ---------------- fallback separate kernels (no cooperative support) ----------------
__global__ __launch_bounds__(256) void u_kernel(
    const float* __restrict__ cost, const float* __restrict__ v, float* __restrict__ u, int it0)
{
  u_body(blockIdx.x * 8 + (threadIdx.x >> 6) * 2, threadIdx.x & 63, it0 != 0, cost, v, u);
}
__global__ __launch_bounds__(256) void v_kernel(
    const float* __restrict__ cost, const float* __restrict__ costT, int useT,
    const float* __restrict__ filter, const float* __restrict__ u, float* __restrict__ v)
{
  v_body(blockIdx.x * 8 + (threadIdx.x >> 6) * 2, threadIdx.x & 63, cost, costT, useT, filter, u, v);
}
__global__ __launch_bounds__(256) void p_kernel(
    float* __restrict__ P, const float* __restrict__ u, const float* __restrict__ v,
    float* __restrict__ idxOut)
{
  p_body(blockIdx.x * 8 + (threadIdx.x >> 6) * 2, threadIdx.x & 63, P, u, v, idxOut);
}

extern "C" void kernel_launch(void* const* d_in, const int* in_sizes, int n_in,
                              void* d_out, int out_size, void* d_ws, size_t ws_size,
                              hipStream_t stream) {
  const float* preds   = (const float*)d_in[0];
  const float* targets = (const float*)d_in[1];
  const float* filter  = (const float*)d_in[2];
  float* out = (float*)d_out;
  float* idxOut = out;
  float* P = out + (size_t)BB*QQ;   // cost lives here until p phase

  const size_t F16A  = (size_t)BB*QQ*DD;
  const size_t f16tot = 4 * F16A * sizeof(f16);
  const size_t smallb = (size_t)4 * 16384 * sizeof(float);
  const size_t costTB = (size_t)BB * QQ * TT * sizeof(float);

  char* p = (char*)d_ws;
  int useF16 = ws_size >= f16tot + smallb;
  f16 *Ahi, *Alo, *Bhi, *Blo;
  float *x2, *y2, *u, *v, *costT;
  int useT;
  if (useF16) {
    Ahi = (f16*)p; Alo = Ahi + F16A; Bhi = Alo + F16A; Blo = Bhi + F16A;
    x2 = (float*)(p + f16tot); y2 = x2 + 16384; u = y2 + 16384; v = u + 16384;
    useT = ws_size >= f16tot + smallb + costTB;
    costT = (float*)(p + f16tot + smallb);
  } else {
    Ahi = Alo = Bhi = Blo = nullptr;
    x2 = (float*)p; y2 = x2 + 16384; u = y2 + 16384; v = u + 16384;
    useT = ws_size >= smallb + costTB;
    costT = (float*)(p + smallb);
  }

  dim3 cg_(TT/128, QQ/128, BB);
  if (useF16) {
    cvt_kernel<<<BB*(QQ+TT)/4, 256, 0, stream>>>(preds, targets, Ahi, Alo, Bhi, Blo, x2, y2);
    cost_mfma_kernel<<<cg_, 256, 0, stream>>>(Ahi, Alo, Bhi, Blo, x2, y2, filter, P, costT, useT);
  } else {
    norms_kernel<<<BB*(QQ+TT), 64, 0, stream>>>(preds, targets, x2, y2);
    cost_fp32_kernel<<<cg_, 256, 0, stream>>>(preds, targets, x2, y2, filter, P, costT, useT);
  }

  int coop = 0, dev = 0;
  (void)hipGetDevice(&dev);
  (void)hipDeviceGetAttribute(&coop, hipDeviceAttributeCooperativeLaunch, dev);
  if (coop) {
    int G = 1024;  // guaranteed co-resident by __launch_bounds__(256,4) on 256 CUs
    int ncu = 0;
    if (hipDeviceGetAttribute(&ncu, hipDeviceAttributeMultiprocessorCount, dev) == hipSuccess && ncu > 0) {
      int nb = 0;
      if (hipOccupancyMaxActiveBlocksPerMultiprocessor(&nb, (const void*)sweep_kernel, 256, 0) == hipSuccess && nb > 0) {
        G = nb * ncu;
        if (G > 1024) G = 1024;
      }
    }
    void* args[] = { (void*)&P, (void*)&costT, (void*)&useT, (void*)&filter,
                     (void*)&u, (void*)&v, (void*)&idxOut, (void*)&G };
    (void)hipLaunchCooperativeKernel((const void*)sweep_kernel, dim3(G), dim3(256), args, 0, stream);
  } else {
    int blks = BB*QQ/8;
    for (int it = 0; it < SINK_ITERS; ++it) {
      u_kernel<<<blks, 256, 0, stream>>>(P, v, u, it == 0 ? 1 : 0);
      v_kernel<<<blks, 256, 0, stream>>>(P, costT, useT, filter, u, v);
    }
    p_kernel<<<blks, 256, 0, stream>>>(P, u, v, idxOut);
  }
}

// Round 7
// 267.942 us; speedup vs baseline: 3.1054x; 3.1054x over previous
//
#include <hip/hip_runtime.h>
#include <math.h>

#define BB 16
#define QQ 1024
#define TT 1024
#define DD 256
#define EPS 0.1f
#define SINK_ITERS 5
// FC replaces 2*max(cost); it cancels algebraically (filtered col: v_t = FC - lse;
// consumers subtract it back). Needs FC >> max(cost)+2; max cost ~40.
#define FCONST 128.0f
#define K2 14.426950408889634f        // (1/eps) * log2(e)
#define EPSLN2 0.069314718055994531f  // eps * ln(2)

typedef _Float16 f16;
typedef _Float16 f16x4 __attribute__((ext_vector_type(4)));
typedef _Float16 f16x8 __attribute__((ext_vector_type(8)));
typedef float f32x4 __attribute__((ext_vector_type(4)));

__device__ __forceinline__ float fast_exp2(float x) {
#if __has_builtin(__builtin_amdgcn_exp2f)
  return __builtin_amdgcn_exp2f(x);
#else
  return exp2f(x);
#endif
}
__device__ __forceinline__ float fast_log2(float x) {
#if __has_builtin(__builtin_amdgcn_logf)
  return __builtin_amdgcn_logf(x);
#else
  return log2f(x);
#endif
}

// ---------------- cvt: fp32 -> (hi,lo) f16 split + fused row norms ----------------
__global__ __launch_bounds__(256) void cvt_kernel(
    const float* __restrict__ preds, const float* __restrict__ targets,
    f16* __restrict__ Ahi, f16* __restrict__ Alo,
    f16* __restrict__ Bhi, f16* __restrict__ Blo,
    float* __restrict__ x2, float* __restrict__ y2)
{
  int w = threadIdx.x >> 6, l = threadIdx.x & 63;
  int row = blockIdx.x * 4 + w;
  const float* src; f16 *hi, *lo; float* nrm;
  if (row < BB*QQ) {
    src = preds + (size_t)row * DD;
    hi = Ahi + (size_t)row * DD; lo = Alo + (size_t)row * DD; nrm = x2 + row;
  } else {
    int r = row - BB*QQ;
    src = targets + (size_t)r * DD;
    hi = Bhi + (size_t)r * DD; lo = Blo + (size_t)r * DD; nrm = y2 + r;
  }
  float4 v = ((const float4*)src)[l];
  f16x4 h, lw;
  h.x = (f16)v.x; h.y = (f16)v.y; h.z = (f16)v.z; h.w = (f16)v.w;
  lw.x = (f16)(v.x - (float)h.x); lw.y = (f16)(v.y - (float)h.y);
  lw.z = (f16)(v.z - (float)h.z); lw.w = (f16)(v.w - (float)h.w);
  *(f16x4*)(hi + l*4) = h;
  *(f16x4*)(lo + l*4) = lw;
  float s = v.x*v.x + v.y*v.y + v.z*v.z + v.w*v.w;
  #pragma unroll
  for (int o = 32; o; o >>= 1) s += __shfl_down(s, o, 64);
  if (l == 0) *nrm = s;
}

// ---------------- per-batch filter scan: cidx (compacted pos), nU, first filtered ----------------
__global__ __launch_bounds__(256) void scan_kernel(
    const float* __restrict__ filter, int* __restrict__ nU,
    int* __restrict__ f0i, int* __restrict__ cidx)
{
  __shared__ int sc[256];
  __shared__ int sf0;
  int b = blockIdx.x, tid = threadIdx.x;
  if (tid == 0) sf0 = 0x7fffffff;
  __syncthreads();
  float4 f4 = ((const float4*)(filter + (size_t)b*TT))[tid];
  int i0 = f4.x > 0.f, i1 = f4.y > 0.f, i2 = f4.z > 0.f, i3 = f4.w > 0.f;
  int cnt = i0+i1+i2+i3;
  int t0 = tid*4;
  int lf = 0x7fffffff;
  if (!i0) lf = t0; else if (!i1) lf = t0+1; else if (!i2) lf = t0+2; else if (!i3) lf = t0+3;
  if (lf != 0x7fffffff) atomicMin(&sf0, lf);
  sc[tid] = cnt;
  __syncthreads();
  for (int off = 1; off < 256; off <<= 1) {
    int val = (tid >= off) ? sc[tid-off] : 0;
    __syncthreads();
    sc[tid] += val;
    __syncthreads();
  }
  int excl = sc[tid] - cnt;
  int* cb = cidx + (size_t)b*TT + t0;
  int run = excl;
  cb[0] = run; run += i0;
  cb[1] = run; run += i1;
  cb[2] = run; run += i2;
  cb[3] = run; run += i3;
  if (tid == 255) nU[b] = sc[255];
  __syncthreads();
  if (tid == 0) f0i[b] = sf0;
}

// ---------------- MFMA cost kernel: 128x128 tile, 64x64/wave, 16x16x32 f16 ----------------
__global__ __launch_bounds__(256) void cost_mfma_kernel(
    const f16* __restrict__ Ahi, const f16* __restrict__ Alo,
    const f16* __restrict__ Bhi, const f16* __restrict__ Blo,
    const float* __restrict__ x2, const float* __restrict__ y2,
    const float* __restrict__ filter,
    float* __restrict__ cost, float* __restrict__ costT, int useT,
    float* __restrict__ costC, const int* __restrict__ cidx, int compact)
{
  __shared__ f16 sA[2][128*32];
  __shared__ f16 sB[2][128*32];
  int b = blockIdx.z;
  int q0 = blockIdx.y * 128, t0 = blockIdx.x * 128;
  int tid = threadIdx.x, w = tid >> 6, l = tid & 63;
  int rq = (w >> 1) * 64, rt = (w & 1) * 64;
  int fr = l & 15, fg = l >> 4;
  const f16* pA[2] = { Ahi + ((size_t)b*QQ + q0) * DD, Alo + ((size_t)b*QQ + q0) * DD };
  const f16* pB[2] = { Bhi + ((size_t)b*TT + t0) * DD, Blo + ((size_t)b*TT + t0) * DD };
  f32x4 acc[4][4] = {};
  for (int k0 = 0; k0 < DD; k0 += 32) {
    __syncthreads();
#if __has_builtin(__builtin_amdgcn_global_load_lds)
    #pragma unroll
    for (int j = 0; j < 2; ++j) {
      int chunk = w*128 + j*64 + l;
      int row = chunk >> 2, kc = chunk & 3;
      size_t go = (size_t)row * DD + k0 + kc*8;
      int lb = (w*128 + j*64) * 8;
      #pragma unroll
      for (int h = 0; h < 2; ++h) {
        __builtin_amdgcn_global_load_lds(
            (const __attribute__((address_space(1))) void*)(pA[h] + go),
            (__attribute__((address_space(3))) void*)&sA[h][lb], 16, 0, 0);
        __builtin_amdgcn_global_load_lds(
            (const __attribute__((address_space(1))) void*)(pB[h] + go),
            (__attribute__((address_space(3))) void*)&sB[h][lb], 16, 0, 0);
      }
    }
#else
    #pragma unroll
    for (int j = 0; j < 2; ++j) {
      int chunk = w*128 + j*64 + l;
      int row = chunk >> 2, kc = chunk & 3;
      size_t go = (size_t)row * DD + k0 + kc*8;
      #pragma unroll
      for (int h = 0; h < 2; ++h) {
        *(f16x8*)&sA[h][chunk*8] = *(const f16x8*)(pA[h] + go);
        *(f16x8*)&sB[h][chunk*8] = *(const f16x8*)(pB[h] + go);
      }
    }
#endif
    __syncthreads();
    f16x8 ah[4], al[4], bh[4], bl[4];
    #pragma unroll
    for (int f = 0; f < 4; ++f) {
      int ao = (rq + f*16 + fr)*32 + fg*8;
      ah[f] = *(const f16x8*)&sA[0][ao];
      al[f] = *(const f16x8*)&sA[1][ao];
      int bo = (rt + f*16 + fr)*32 + fg*8;
      bh[f] = *(const f16x8*)&sB[0][bo];
      bl[f] = *(const f16x8*)&sB[1][bo];
    }
    #pragma unroll
    for (int fm = 0; fm < 4; ++fm)
      #pragma unroll
      for (int fn = 0; fn < 4; ++fn) {
        acc[fm][fn] = __builtin_amdgcn_mfma_f32_16x16x32_f16(ah[fm], bh[fn], acc[fm][fn], 0, 0, 0);
        acc[fm][fn] = __builtin_amdgcn_mfma_f32_16x16x32_f16(ah[fm], bl[fn], acc[fm][fn], 0, 0, 0);
        acc[fm][fn] = __builtin_amdgcn_mfma_f32_16x16x32_f16(al[fm], bh[fn], acc[fm][fn], 0, 0, 0);
      }
  }
  float xv[16];
  #pragma unroll
  for (int fm = 0; fm < 4; ++fm)
    #pragma unroll
    for (int r = 0; r < 4; ++r)
      xv[fm*4+r] = x2[(size_t)b*QQ + q0 + rq + fm*16 + fg*4 + r];
  float yv[4], fv[4];
  int jn[4];
  #pragma unroll
  for (int fn = 0; fn < 4; ++fn) {
    int t = t0 + rt + fn*16 + fr;
    yv[fn] = y2[(size_t)b*TT + t];
    fv[fn] = filter[(size_t)b*TT + t];
    jn[fn] = compact ? cidx[(size_t)b*TT + t] : 0;
  }
  #pragma unroll
  for (int fm = 0; fm < 4; ++fm) {
    #pragma unroll
    for (int fn = 0; fn < 4; ++fn) {
      int t = t0 + rt + fn*16 + fr;
      float cvr[4];
      #pragma unroll
      for (int r = 0; r < 4; ++r) {
        float c2 = xv[fm*4+r] + yv[fn] - 2.0f*acc[fm][fn][r];
        float craw = sqrtf(fmaxf(c2, 0.f));
        cvr[r] = craw;
        int q = q0 + rq + fm*16 + fg*4 + r;
        if (!compact) {
          cost[((size_t)b*QQ + q)*TT + t] = (fv[fn] <= 0.f) ? FCONST : craw;
        } else if (fv[fn] > 0.f) {
          costC[((size_t)b*QQ + q)*TT + jn[fn]] = craw;
        }
      }
      // filtered columns of costT are never read by v-phase -> skip the write
      if (useT && fv[fn] > 0.f) {
        float* dst = costT + ((size_t)b*TT + t)*QQ + q0 + rq + fm*16 + fg*4;
        *(float4*)dst = make_float4(cvr[0], cvr[1], cvr[2], cvr[3]);
      }
    }
  }
}

// ---------------- fp32 fallback ----------------
__global__ __launch_bounds__(64) void norms_kernel(
    const float* __restrict__ preds, const float* __restrict__ targets,
    float* __restrict__ x2, float* __restrict__ y2)
{
  int row = blockIdx.x;
  const float* src; float* dst;
  if (row < BB*QQ) { src = preds + (size_t)row * DD; dst = x2 + row; }
  else { int r = row - BB*QQ; src = targets + (size_t)r * DD; dst = y2 + r; }
  float4 v = ((const float4*)src)[threadIdx.x];
  float s = v.x*v.x + v.y*v.y + v.z*v.z + v.w*v.w;
  #pragma unroll
  for (int o = 32; o; o >>= 1) s += __shfl_down(s, o, 64);
  if (threadIdx.x == 0) *dst = s;
}

#define LDSTR 132
__global__ __launch_bounds__(256) void cost_fp32_kernel(
    const float* __restrict__ preds, const float* __restrict__ targets,
    const float* __restrict__ x2, const float* __restrict__ y2,
    const float* __restrict__ filter,
    float* __restrict__ cost, float* __restrict__ costT, int useT)
{
  __shared__ float As[16*LDSTR];
  __shared__ float Bs[16*LDSTR];
  int b  = blockIdx.z;
  int q0 = blockIdx.y * 128;
  int t0 = blockIdx.x * 128;
  const float* Ab = preds   + ((size_t)b*QQ + q0) * DD;
  const float* Bb = targets + ((size_t)b*TT + t0) * DD;
  int tid = threadIdx.x;
  int srow = tid >> 2, sq = (tid & 3) << 2;
  int w = tid >> 6, l = tid & 63;
  int rq = ((w >> 1) << 6) + ((l >> 3) << 3);
  int rt = ((w & 1) << 6) + ((l & 7) << 3);
  float acc[8][8] = {};
  for (int k0 = 0; k0 < DD; k0 += 16) {
    float4 a0 = *(const float4*)(Ab + (size_t)srow*DD + k0 + sq);
    float4 a1 = *(const float4*)(Ab + (size_t)(srow+64)*DD + k0 + sq);
    float4 b0 = *(const float4*)(Bb + (size_t)srow*DD + k0 + sq);
    float4 b1 = *(const float4*)(Bb + (size_t)(srow+64)*DD + k0 + sq);
    __syncthreads();
    As[(sq+0)*LDSTR + srow] = a0.x; As[(sq+1)*LDSTR + srow] = a0.y;
    As[(sq+2)*LDSTR + srow] = a0.z; As[(sq+3)*LDSTR + srow] = a0.w;
    As[(sq+0)*LDSTR + srow+64] = a1.x; As[(sq+1)*LDSTR + srow+64] = a1.y;
    As[(sq+2)*LDSTR + srow+64] = a1.z; As[(sq+3)*LDSTR + srow+64] = a1.w;
    Bs[(sq+0)*LDSTR + srow] = b0.x; Bs[(sq+1)*LDSTR + srow] = b0.y;
    Bs[(sq+2)*LDSTR + srow] = b0.z; Bs[(sq+3)*LDSTR + srow] = b0.w;
    Bs[(sq+0)*LDSTR + srow+64] = b1.x; Bs[(sq+1)*LDSTR + srow+64] = b1.y;
    Bs[(sq+2)*LDSTR + srow+64] = b1.z; Bs[(sq+3)*LDSTR + srow+64] = b1.w;
    __syncthreads();
    #pragma unroll
    for (int k = 0; k < 16; ++k) {
      float4 af0 = *(const float4*)&As[k*LDSTR + rq];
      float4 af1 = *(const float4*)&As[k*LDSTR + rq + 4];
      float4 bf0 = *(const float4*)&Bs[k*LDSTR + rt];
      float4 bf1 = *(const float4*)&Bs[k*LDSTR + rt + 4];
      float aa[8] = {af0.x,af0.y,af0.z,af0.w,af1.x,af1.y,af1.z,af1.w};
      float bb[8] = {bf0.x,bf0.y,bf0.z,bf0.w,bf1.x,bf1.y,bf1.z,bf1.w};
      #pragma unroll
      for (int i = 0; i < 8; ++i)
        #pragma unroll
        for (int j = 0; j < 8; ++j)
          acc[i][j] = fmaf(aa[i], bb[j], acc[i][j]);
    }
  }
  float xq[8], yt[8], fvv[8];
  #pragma unroll
  for (int i = 0; i < 8; ++i) xq[i] = x2[(size_t)b*QQ + q0 + rq + i];
  #pragma unroll
  for (int j = 0; j < 8; ++j) {
    yt[j] = y2[(size_t)b*TT + t0 + rt + j];
    fvv[j] = filter[(size_t)b*TT + t0 + rt + j];
  }
  float cv[8][8];
  #pragma unroll
  for (int i = 0; i < 8; ++i)
    #pragma unroll
    for (int j = 0; j < 8; ++j) {
      float c2 = xq[i] + yt[j] - 2.f*acc[i][j];
      float c = sqrtf(fmaxf(c2, 0.f));
      if (fvv[j] <= 0.f) c = FCONST;
      cv[i][j] = c;
    }
  #pragma unroll
  for (int i = 0; i < 8; ++i) {
    float* dst = cost + ((size_t)b*QQ + q0 + rq + i) * TT + t0 + rt;
    *(float4*)dst       = make_float4(cv[i][0], cv[i][1], cv[i][2], cv[i][3]);
    *(float4*)(dst + 4) = make_float4(cv[i][4], cv[i][5], cv[i][6], cv[i][7]);
  }
  if (useT) {
    #pragma unroll
    for (int j = 0; j < 8; ++j) {
      if (fvv[j] <= 0.f) continue;
      float* dst = costT + ((size_t)b*TT + t0 + rt + j) * QQ + q0 + rq;
      *(float4*)dst       = make_float4(cv[0][j], cv[1][j], cv[2][j], cv[3][j]);
      *(float4*)(dst + 4) = make_float4(cv[4][j], cv[5][j], cv[6][j], cv[7][j]);
    }
  }
}

// ---------------- wave reductions ----------------
__device__ __forceinline__ float wave_max64(float v) {
  #pragma unroll
  for (int o = 1; o < 64; o <<= 1) v = fmaxf(v, __shfl_xor(v, o, 64));
  return v;
}
__device__ __forceinline__ float wave_sum64(float v) {
  #pragma unroll
  for (int o = 1; o < 64; o <<= 1) v += __shfl_xor(v, o, 64);
  return v;
}

// ================= COMPACT sweep kernels =================
// u over compacted columns + closed-form filtered tail
__global__ __launch_bounds__(256) void u_c_kernel(
    const float* __restrict__ costC, const float* __restrict__ vC,
    const float* __restrict__ vf, const int* __restrict__ nU,
    float* __restrict__ u, int it0)
{
  int w = threadIdx.x >> 6, l = threadIdx.x & 63;
  int row = blockIdx.x * 8 + w * 2;
  int b = row >> 10;
  int n = nU[b];
  int nF = TT - n;
  const float4* c0 = (const float4*)(costC + (size_t)row * TT);
  const float4* c1 = c0 + TT/4;
  const float4* vb = (const float4*)(vC + (size_t)b * TT);
  float s0[16], s1[16], m0 = -3.0e38f, m1 = -3.0e38f;
  int iters = (n + 255) >> 8;
  #pragma unroll
  for (int i = 0; i < 4; ++i) {
    if (i < iters) {
      int jj = l + (i << 6);
      int j = jj << 2;
      float4 v4;
      if (it0) v4 = make_float4(0.f,0.f,0.f,0.f); else v4 = vb[jj];
      float4 a4 = c0[jj];
      float4 b4 = c1[jj];
      s0[4*i+0] = (j+0 < n) ? (v4.x - a4.x)*K2 : -3.0e38f;
      s0[4*i+1] = (j+1 < n) ? (v4.y - a4.y)*K2 : -3.0e38f;
      s0[4*i+2] = (j+2 < n) ? (v4.z - a4.z)*K2 : -3.0e38f;
      s0[4*i+3] = (j+3 < n) ? (v4.w - a4.w)*K2 : -3.0e38f;
      s1[4*i+0] = (j+0 < n) ? (v4.x - b4.x)*K2 : -3.0e38f;
      s1[4*i+1] = (j+1 < n) ? (v4.y - b4.y)*K2 : -3.0e38f;
      s1[4*i+2] = (j+2 < n) ? (v4.z - b4.z)*K2 : -3.0e38f;
      s1[4*i+3] = (j+3 < n) ? (v4.w - b4.w)*K2 : -3.0e38f;
      m0 = fmaxf(m0, fmaxf(fmaxf(s0[4*i+0], s0[4*i+1]), fmaxf(s0[4*i+2], s0[4*i+3])));
      m1 = fmaxf(m1, fmaxf(fmaxf(s1[4*i+0], s1[4*i+1]), fmaxf(s1[4*i+2], s1[4*i+3])));
    } else {
      #pragma unroll
      for (int k = 0; k < 4; ++k) { s0[4*i+k] = -3.0e38f; s1[4*i+k] = -3.0e38f; }
    }
  }
  float st = 0.f;
  if (nF > 0) {
    float vfb = it0 ? 0.f : vf[b];
    st = (vfb - FCONST) * K2;
    m0 = fmaxf(m0, st); m1 = fmaxf(m1, st);
  }
  m0 = wave_max64(m0); m1 = wave_max64(m1);
  float q0 = 0.f, q1 = 0.f;
  #pragma unroll
  for (int i = 0; i < 16; ++i) { q0 += fast_exp2(s0[i] - m0); q1 += fast_exp2(s1[i] - m1); }
  q0 = wave_sum64(q0); q1 = wave_sum64(q1);
  if (nF > 0) {
    q0 += (float)nF * fast_exp2(st - m0);
    q1 += (float)nF * fast_exp2(st - m1);
  }
  if (l == 0) {
    u[row]   = -EPSLN2 * (m0 + fast_log2(q0));
    u[row+1] = -EPSLN2 * (m1 + fast_log2(q1));
  }
}

// v: R4 logic + write compacted vC and shared filtered value vf
__global__ __launch_bounds__(256) void v_c_kernel(
    const float* __restrict__ costT,
    const float* __restrict__ filter, const int* __restrict__ cidx,
    const float* __restrict__ u, float* __restrict__ v,
    float* __restrict__ vC, float* __restrict__ vf)
{
  int w = threadIdx.x >> 6, l = threadIdx.x & 63;
  int row = blockIdx.x * 8 + w * 2;
  int b = row >> 10;
  const float4* ub = (const float4*)(u + (size_t)b * QQ);
  bool f0 = (filter[row]   <= 0.f);
  bool f1 = (filter[row+1] <= 0.f);
  float4 uw[4];
  #pragma unroll
  for (int i = 0; i < 4; ++i) uw[i] = ub[l + (i << 6)];
  float s0[16], s1[16], m0 = -3.0e38f, m1 = -3.0e38f;
  if (f0) {
    #pragma unroll
    for (int i = 0; i < 4; ++i) {
      s0[4*i+0] = (uw[i].x - FCONST) * K2; s0[4*i+1] = (uw[i].y - FCONST) * K2;
      s0[4*i+2] = (uw[i].z - FCONST) * K2; s0[4*i+3] = (uw[i].w - FCONST) * K2;
    }
  } else {
    const float4* cr = (const float4*)(costT + (size_t)row * QQ);
    #pragma unroll
    for (int i = 0; i < 4; ++i) {
      float4 c4 = cr[l + (i << 6)];
      s0[4*i+0] = (uw[i].x - c4.x) * K2; s0[4*i+1] = (uw[i].y - c4.y) * K2;
      s0[4*i+2] = (uw[i].z - c4.z) * K2; s0[4*i+3] = (uw[i].w - c4.w) * K2;
    }
  }
  if (f1) {
    #pragma unroll
    for (int i = 0; i < 4; ++i) {
      s1[4*i+0] = (uw[i].x - FCONST) * K2; s1[4*i+1] = (uw[i].y - FCONST) * K2;
      s1[4*i+2] = (uw[i].z - FCONST) * K2; s1[4*i+3] = (uw[i].w - FCONST) * K2;
    }
  } else {
    const float4* cr = (const float4*)(costT + (size_t)(row+1) * QQ);
    #pragma unroll
    for (int i = 0; i < 4; ++i) {
      float4 c4 = cr[l + (i << 6)];
      s1[4*i+0] = (uw[i].x - c4.x) * K2; s1[4*i+1] = (uw[i].y - c4.y) * K2;
      s1[4*i+2] = (uw[i].z - c4.z) * K2; s1[4*i+3] = (uw[i].w - c4.w) * K2;
    }
  }
  #pragma unroll
  for (int i = 0; i < 16; ++i) { m0 = fmaxf(m0, s0[i]); m1 = fmaxf(m1, s1[i]); }
  m0 = wave_max64(m0); m1 = wave_max64(m1);
  float q0 = 0.f, q1 = 0.f;
  #pragma unroll
  for (int i = 0; i < 16; ++i) { q0 += fast_exp2(s0[i] - m0); q1 += fast_exp2(s1[i] - m1); }
  q0 = wave_sum64(q0); q1 = wave_sum64(q1);
  if (l == 0) {
    float val0 = -EPSLN2 * (m0 + fast_log2(q0));
    float val1 = -EPSLN2 * (m1 + fast_log2(q1));
    v[row]   = val0;
    v[row+1] = val1;
    if (f0) vf[b] = val0; else vC[(size_t)b*TT + cidx[row]] = val0;
    if (f1) vf[b] = val1; else vC[(size_t)b*TT + cidx[row+1]] = val1;
  }
}

// p: gather compacted cost, splat constant filtered P, merged argmax
__global__ __launch_bounds__(256) void p_c_kernel(
    const float* __restrict__ costC, const float* __restrict__ filter,
    const int* __restrict__ cidx, const int* __restrict__ nU,
    const int* __restrict__ f0i, const float* __restrict__ vf,
    const float* __restrict__ u, const float* __restrict__ v,
    float* __restrict__ P, float* __restrict__ idxOut)
{
  int w = threadIdx.x >> 6, l = threadIdx.x & 63;
  int row = blockIdx.x * 8 + w * 2;
  int b = row >> 10;
  int nF = TT - nU[b];
  float u0 = u[row], u1 = u[row+1];
  float pf0 = -1.f, pf1 = -1.f; int fidx = 0x7fffffff;
  if (nF > 0) {
    float vfb = vf[b];
    pf0 = fast_exp2((u0 + vfb - FCONST) * K2);
    pf1 = fast_exp2((u1 + vfb - FCONST) * K2);
    fidx = f0i[b];
  }
  const float* r0 = costC + (size_t)row * TT;
  const float* r1 = r0 + TT;
  float4* o0 = (float4*)(P + (size_t)row * TT);
  float4* o1 = o0 + TT/4;
  const float4* fb = (const float4*)(filter + (size_t)b * TT);
  const int4*   jb = (const int4*)(cidx + (size_t)b * TT);
  const float4* vv = (const float4*)(v + (size_t)b * TT);
  float bp0 = -1.f, bp1 = -1.f; int bt0 = 0x7ffffffe, bt1 = 0x7ffffffe;
  #pragma unroll
  for (int i = 0; i < 4; ++i) {
    int e = l + (i << 6);
    float4 f4 = fb[e];
    int4  j4 = jb[e];
    float4 v4 = vv[e];
    int tb = e << 2;
    float4 p0, p1;
#define PELEM(comp, jx, toff) \
    if (f4.comp > 0.f) { \
      float cA = r0[jx], cB = r1[jx]; \
      p0.comp = fast_exp2((u0 + v4.comp - cA) * K2); \
      p1.comp = fast_exp2((u1 + v4.comp - cB) * K2); \
      if (p0.comp > bp0) { bp0 = p0.comp; bt0 = tb + toff; } \
      if (p1.comp > bp1) { bp1 = p1.comp; bt1 = tb + toff; } \
    } else { p0.comp = pf0; p1.comp = pf1; }
    PELEM(x, j4.x, 0)
    PELEM(y, j4.y, 1)
    PELEM(z, j4.z, 2)
    PELEM(w, j4.w, 3)
#undef PELEM
    o0[e] = p0;
    o1[e] = p1;
  }
  #pragma unroll
  for (int o = 1; o < 64; o <<= 1) {
    float op = __shfl_xor(bp0, o, 64);
    int   ot = __shfl_xor(bt0, o, 64);
    if (op > bp0 || (op == bp0 && ot < bt0)) { bp0 = op; bt0 = ot; }
    op = __shfl_xor(bp1, o, 64);
    ot = __shfl_xor(bt1, o, 64);
    if (op > bp1 || (op == bp1 && ot < bt1)) { bp1 = op; bt1 = ot; }
  }
  if (l == 0) {
    if (pf0 > bp0 || (pf0 == bp0 && fidx < bt0)) bt0 = fidx;
    if (pf1 > bp1 || (pf1 == bp1 && fidx < bt1)) bt1 = fidx;
    idxOut[row]   = (float)bt0;
    idxOut[row+1] = (float)bt1;
  }
}

// ================= R4 fallback sweep kernels (full cost matrix) =================
__device__ __forceinline__ void u_body(int row, int l, bool it0,
    const float* __restrict__ cost, const float* __restrict__ v, float* __restrict__ u)
{
  int b = row >> 10;
  const float4* c0 = (const float4*)(cost + (size_t)row * TT);
  const float4* c1 = c0 + TT/4;
  const float4* vb = (const float4*)(v + (size_t)b * TT);
  float s0[16], s1[16], m0 = -3.0e38f, m1 = -3.0e38f;
  #pragma unroll
  for (int i = 0; i < 4; ++i) {
    float4 v4;
    if (it0) v4 = make_float4(0.f, 0.f, 0.f, 0.f);
    else     v4 = vb[l + (i << 6)];
    float4 a4 = c0[l + (i << 6)];
    float4 b4 = c1[l + (i << 6)];
    s0[4*i+0] = (v4.x - a4.x) * K2; s0[4*i+1] = (v4.y - a4.y) * K2;
    s0[4*i+2] = (v4.z - a4.z) * K2; s0[4*i+3] = (v4.w - a4.w) * K2;
    s1[4*i+0] = (v4.x - b4.x) * K2; s1[4*i+1] = (v4.y - b4.y) * K2;
    s1[4*i+2] = (v4.z - b4.z) * K2; s1[4*i+3] = (v4.w - b4.w) * K2;
    m0 = fmaxf(m0, fmaxf(fmaxf(s0[4*i+0], s0[4*i+1]), fmaxf(s0[4*i+2], s0[4*i+3])));
    m1 = fmaxf(m1, fmaxf(fmaxf(s1[4*i+0], s1[4*i+1]), fmaxf(s1[4*i+2], s1[4*i+3])));
  }
  m0 = wave_max64(m0); m1 = wave_max64(m1);
  float q0 = 0.f, q1 = 0.f;
  #pragma unroll
  for (int i = 0; i < 16; ++i) { q0 += fast_exp2(s0[i] - m0); q1 += fast_exp2(s1[i] - m1); }
  q0 = wave_sum64(q0); q1 = wave_sum64(q1);
  if (l == 0) {
    u[row]   = -EPSLN2 * (m0 + fast_log2(q0));
    u[row+1] = -EPSLN2 * (m1 + fast_log2(q1));
  }
}

__global__ __launch_bounds__(256) void u_kernel(
    const float* __restrict__ cost, const float* __restrict__ v, float* __restrict__ u, int it0)
{
  u_body(blockIdx.x * 8 + (threadIdx.x >> 6) * 2, threadIdx.x & 63, it0 != 0, cost, v, u);
}

__global__ __launch_bounds__(256) void v_kernel(
    const float* __restrict__ cost, const float* __restrict__ costT, int useT,
    const float* __restrict__ filter, const float* __restrict__ u, float* __restrict__ v)
{
  int w = threadIdx.x >> 6, l = threadIdx.x & 63;
  int row = blockIdx.x * 8 + w * 2;
  int b = row >> 10, t = row & 1023;
  const float4* ub = (const float4*)(u + (size_t)b * QQ);
  bool f0 = (filter[row]   <= 0.f);
  bool f1 = (filter[row+1] <= 0.f);
  float4 uw[4];
  #pragma unroll
  for (int i = 0; i < 4; ++i) uw[i] = ub[l + (i << 6)];
  float s0[16], s1[16], m0 = -3.0e38f, m1 = -3.0e38f;
  if (f0) {
    #pragma unroll
    for (int i = 0; i < 4; ++i) {
      s0[4*i+0] = (uw[i].x - FCONST) * K2; s0[4*i+1] = (uw[i].y - FCONST) * K2;
      s0[4*i+2] = (uw[i].z - FCONST) * K2; s0[4*i+3] = (uw[i].w - FCONST) * K2;
    }
  } else if (useT) {
    const float4* cr = (const float4*)(costT + (size_t)row * QQ);
    #pragma unroll
    for (int i = 0; i < 4; ++i) {
      float4 c4 = cr[l + (i << 6)];
      s0[4*i+0] = (uw[i].x - c4.x) * K2; s0[4*i+1] = (uw[i].y - c4.y) * K2;
      s0[4*i+2] = (uw[i].z - c4.z) * K2; s0[4*i+3] = (uw[i].w - c4.w) * K2;
    }
  } else {
    const float* cr = cost + (size_t)b*QQ*TT + t;
    #pragma unroll
    for (int i = 0; i < 4; ++i) {
      int q = (l + (i << 6)) << 2;
      s0[4*i+0] = (uw[i].x - cr[(size_t)(q+0)*TT]) * K2;
      s0[4*i+1] = (uw[i].y - cr[(size_t)(q+1)*TT]) * K2;
      s0[4*i+2] = (uw[i].z - cr[(size_t)(q+2)*TT]) * K2;
      s0[4*i+3] = (uw[i].w - cr[(size_t)(q+3)*TT]) * K2;
    }
  }
  if (f1) {
    #pragma unroll
    for (int i = 0; i < 4; ++i) {
      s1[4*i+0] = (uw[i].x - FCONST) * K2; s1[4*i+1] = (uw[i].y - FCONST) * K2;
      s1[4*i+2] = (uw[i].z - FCONST) * K2; s1[4*i+3] = (uw[i].w - FCONST) * K2;
    }
  } else if (useT) {
    const float4* cr = (const float4*)(costT + (size_t)(row+1) * QQ);
    #pragma unroll
    for (int i = 0; i < 4; ++i) {
      float4 c4 = cr[l + (i << 6)];
      s1[4*i+0] = (uw[i].x - c4.x) * K2; s1[4*i+1] = (uw[i].y - c4.y) * K2;
      s1[4*i+2] = (uw[i].z - c4.z) * K2; s1[4*i+3] = (uw[i].w - c4.w) * K2;
    }
  } else {
    const float* cr = cost + (size_t)b*QQ*TT + t + 1;
    #pragma unroll
    for (int i = 0; i < 4; ++i) {
      int q = (l + (i << 6)) << 2;
      s1[4*i+0] = (uw[i].x - cr[(size_t)(q+0)*TT]) * K2;
      s1[4*i+1] = (uw[i].y - cr[(size_t)(q+1)*TT]) * K2;
      s1[4*i+2] = (uw[i].z - cr[(size_t)(q+2)*TT]) * K2;
      s1[4*i+3] = (uw[i].w - cr[(size_t)(q+3)*TT]) * K2;
    }
  }
  #pragma unroll
  for (int i = 0; i < 16; ++i) { m0 = fmaxf(m0, s0[i]); m1 = fmaxf(m1, s1[i]); }
  m0 = wave_max64(m0); m1 = wave_max64(m1);
  float q0 = 0.f, q1 = 0.f;
  #pragma unroll
  for (int i = 0; i < 16; ++i) { q0 += fast_exp2(s0[i] - m0); q1 += fast_exp2(s1[i] - m1); }
  q0 = wave_sum64(q0); q1 = wave_sum64(q1);
  if (l == 0) {
    v[row]   = -EPSLN2 * (m0 + fast_log2(q0));
    v[row+1] = -EPSLN2 * (m1 + fast_log2(q1));
  }
}

__global__ __launch_bounds__(256) void p_kernel(
    float* __restrict__ P, const float* __restrict__ u, const float* __restrict__ v,
    float* __restrict__ idxOut)
{
  int w = threadIdx.x >> 6, l = threadIdx.x & 63;
  int row = blockIdx.x * 8 + w * 2;
  int b = row >> 10;
  float4* c0 = (float4*)(P + (size_t)row * TT);
  float4* c1 = c0 + TT/4;
  const float4* vb = (const float4*)(v + (size_t)b * TT);
  float u0 = u[row], u1 = u[row+1];
  float bp0 = -1.f, bp1 = -1.f; int bt0 = 0, bt1 = 0;
  #pragma unroll
  for (int i = 0; i < 4; ++i) {
    float4 v4 = vb[l + (i << 6)];
    float4 a4 = c0[l + (i << 6)];
    float4 b4 = c1[l + (i << 6)];
    int t0 = (l + (i << 6)) << 2;
    float4 p0, p1;
    p0.x = fast_exp2((u0 + v4.x - a4.x) * K2);
    p0.y = fast_exp2((u0 + v4.y - a4.y) * K2);
    p0.z = fast_exp2((u0 + v4.z - a4.z) * K2);
    p0.w = fast_exp2((u0 + v4.w - a4.w) * K2);
    p1.x = fast_exp2((u1 + v4.x - b4.x) * K2);
    p1.y = fast_exp2((u1 + v4.y - b4.y) * K2);
    p1.z = fast_exp2((u1 + v4.z - b4.z) * K2);
    p1.w = fast_exp2((u1 + v4.w - b4.w) * K2);
    if (p0.x > bp0) { bp0 = p0.x; bt0 = t0 + 0; }
    if (p0.y > bp0) { bp0 = p0.y; bt0 = t0 + 1; }
    if (p0.z > bp0) { bp0 = p0.z; bt0 = t0 + 2; }
    if (p0.w > bp0) { bp0 = p0.w; bt0 = t0 + 3; }
    if (p1.x > bp1) { bp1 = p1.x; bt1 = t0 + 0; }
    if (p1.y > bp1) { bp1 = p1.y; bt1 = t0 + 1; }
    if (p1.z > bp1) { bp1 = p1.z; bt1 = t0 + 2; }
    if (p1.w > bp1) { bp1 = p1.w; bt1 = t0 + 3; }
    c0[l + (i << 6)] = p0;
    c1[l + (i << 6)] = p1;
  }
  #pragma unroll
  for (int o = 1; o < 64; o <<= 1) {
    float op = __shfl_xor(bp0, o, 64);
    int   ot = __shfl_xor(bt0, o, 64);
    if (op > bp0 || (op == bp0 && ot < bt0)) { bp0 = op; bt0 = ot; }
    op = __shfl_xor(bp1, o, 64);
    ot = __shfl_xor(bt1, o, 64);
    if (op > bp1 || (op == bp1 && ot < bt1)) { bp1 = op; bt1 = ot; }
  }
  if (l == 0) { idxOut[row] = (float)bt0; idxOut[row+1] = (float)bt1; }
}

extern "C" void kernel_launch(void* const* d_in, const int* in_sizes, int n_in,
                              void* d_out, int out_size, void* d_ws, size_t ws_size,
                              hipStream_t stream) {
  const float* preds   = (const float*)d_in[0];
  const float* targets = (const float*)d_in[1];
  const float* filter  = (const float*)d_in[2];
  float* out = (float*)d_out;
  float* idxOut = out;
  float* P = out + (size_t)BB*QQ;   // full-cost mode: cost lives here until p phase

  const size_t F16A   = (size_t)BB*QQ*DD;
  const size_t f16tot = 4 * F16A * sizeof(f16);          // 33.55 MB
  const size_t SMALL  = (size_t)1 << 19;                 // 512 KB scratch for small arrays
  const size_t CB     = (size_t)BB * QQ * TT * sizeof(float);  // 67.1 MB

  char* ws = (char*)d_ws;
  int useF16 = ws_size >= f16tot + SMALL;
  char* base = ws + (useF16 ? f16tot : 0);
  f16 *Ahi = (f16*)ws, *Alo = Ahi + F16A, *Bhi = Alo + F16A, *Blo = Bhi + F16A;
  float* x2 = (float*)base;
  float* y2 = x2 + 16384;
  float* u  = y2 + 16384;
  float* v  = u + 16384;
  float* vC = v + 16384;
  float* vf = vC + 16384;          // 16 floats
  int* nU   = (int*)(vf + 64);
  int* f0i  = nU + 64;
  int* cidx = f0i + 64;            // 16384 ints — all fits in 512 KB
  float* costT = (float*)(base + SMALL);
  float* costC = (float*)(base + SMALL + CB);
  int useT = ws_size >= (size_t)(base - ws) + SMALL + CB;
  int useC = useF16 && (ws_size >= f16tot + SMALL + 2*CB);

  dim3 cg_(TT/128, QQ/128, BB);
  if (useF16) {
    cvt_kernel<<<BB*(QQ+TT)/4, 256, 0, stream>>>(preds, targets, Ahi, Alo, Bhi, Blo, x2, y2);
    if (useC) scan_kernel<<<BB, 256, 0, stream>>>(filter, nU, f0i, cidx);
    cost_mfma_kernel<<<cg_, 256, 0, stream>>>(Ahi, Alo, Bhi, Blo, x2, y2, filter,
                                              P, costT, useT, costC, cidx, useC);
  } else {
    norms_kernel<<<BB*(QQ+TT), 64, 0, stream>>>(preds, targets, x2, y2);
    cost_fp32_kernel<<<cg_, 256, 0, stream>>>(preds, targets, x2, y2, filter, P, costT, useT);
  }

  int blks = BB*QQ/8;
  if (useC) {
    for (int it = 0; it < SINK_ITERS; ++it) {
      u_c_kernel<<<blks, 256, 0, stream>>>(costC, vC, vf, nU, u, it == 0 ? 1 : 0);
      v_c_kernel<<<blks, 256, 0, stream>>>(costT, filter, cidx, u, v, vC, vf);
    }
    p_c_kernel<<<blks, 256, 0, stream>>>(costC, filter, cidx, nU, f0i, vf, u, v, P, idxOut);
  } else {
    for (int it = 0; it < SINK_ITERS; ++it) {
      u_kernel<<<blks, 256, 0, stream>>>(P, v, u, it == 0 ? 1 : 0);
      v_kernel<<<blks, 256, 0, stream>>>(P, costT, useT, filter, u, v);
    }
    p_kernel<<<blks, 256, 0, stream>>>(P, u, v, idxOut);
  }
}

// Round 8
// 260.258 us; speedup vs baseline: 3.1971x; 1.0295x over previous
//
#include <hip/hip_runtime.h>
#include <math.h>

#define BB 16
#define QQ 1024
#define TT 1024
#define DD 256
#define EPS 0.1f
#define SINK_ITERS 5
// FC replaces 2*max(cost); cancels algebraically (filtered col: v_t = FC - lse;
// consumers subtract it back). Needs FC >> max(cost)+2; max cost ~40.
#define FCONST 128.0f
#define K2 14.426950408889634f        // (1/eps) * log2(e)
#define EPSLN2 0.069314718055994531f  // eps * ln(2)

typedef _Float16 f16;
typedef _Float16 f16x4 __attribute__((ext_vector_type(4)));
typedef _Float16 f16x8 __attribute__((ext_vector_type(8)));
typedef float f32x4 __attribute__((ext_vector_type(4)));

__device__ __forceinline__ float fast_exp2(float x) {
#if __has_builtin(__builtin_amdgcn_exp2f)
  return __builtin_amdgcn_exp2f(x);
#else
  return exp2f(x);
#endif
}
__device__ __forceinline__ float fast_log2(float x) {
#if __has_builtin(__builtin_amdgcn_logf)
  return __builtin_amdgcn_logf(x);
#else
  return log2f(x);
#endif
}

// ---------------- per-batch filter scan: cidx (compacted pos), nU, first filtered ----------------
__global__ __launch_bounds__(256) void scan_kernel(
    const float* __restrict__ filter, int* __restrict__ nU,
    int* __restrict__ f0i, int* __restrict__ cidx)
{
  __shared__ int sc[256];
  __shared__ int sf0;
  int b = blockIdx.x, tid = threadIdx.x;
  if (tid == 0) sf0 = 0x7fffffff;
  __syncthreads();
  float4 f4 = ((const float4*)(filter + (size_t)b*TT))[tid];
  int i0 = f4.x > 0.f, i1 = f4.y > 0.f, i2 = f4.z > 0.f, i3 = f4.w > 0.f;
  int cnt = i0+i1+i2+i3;
  int t0 = tid*4;
  int lf = 0x7fffffff;
  if (!i0) lf = t0; else if (!i1) lf = t0+1; else if (!i2) lf = t0+2; else if (!i3) lf = t0+3;
  if (lf != 0x7fffffff) atomicMin(&sf0, lf);
  sc[tid] = cnt;
  __syncthreads();
  for (int off = 1; off < 256; off <<= 1) {
    int val = (tid >= off) ? sc[tid-off] : 0;
    __syncthreads();
    sc[tid] += val;
    __syncthreads();
  }
  int excl = sc[tid] - cnt;
  int* cb = cidx + (size_t)b*TT + t0;
  int run = excl;
  cb[0] = run; run += i0;
  cb[1] = run; run += i1;
  cb[2] = run; run += i2;
  cb[3] = run; run += i3;
  if (tid == 255) nU[b] = sc[255];
  __syncthreads();
  if (tid == 0) f0i[b] = sf0;
}

// ---------------- cvt COMPACT: preds as-is; targets written in compacted order ----------------
__global__ __launch_bounds__(256) void cvt_c_kernel(
    const float* __restrict__ preds, const float* __restrict__ targets,
    const float* __restrict__ filter, const int* __restrict__ cidx,
    f16* __restrict__ Ahi, f16* __restrict__ Alo,
    f16* __restrict__ Bhi, f16* __restrict__ Blo,
    float* __restrict__ x2, float* __restrict__ y2)
{
  int w = threadIdx.x >> 6, l = threadIdx.x & 63;
  int row = blockIdx.x * 4 + w;
  const float* src; f16 *hi, *lo; float* nrm;
  if (row < BB*QQ) {
    src = preds + (size_t)row * DD;
    hi = Ahi + (size_t)row * DD; lo = Alo + (size_t)row * DD; nrm = x2 + row;
  } else {
    int r = row - BB*QQ;
    if (filter[r] <= 0.f) return;          // wave-uniform: filtered targets never needed
    int b = r >> 10;
    int cj = cidx[r];
    size_t crow = (size_t)b*TT + cj;
    src = targets + (size_t)r * DD;
    hi = Bhi + crow * DD; lo = Blo + crow * DD; nrm = y2 + crow;
  }
  float4 v = ((const float4*)src)[l];
  f16x4 h, lw;
  h.x = (f16)v.x; h.y = (f16)v.y; h.z = (f16)v.z; h.w = (f16)v.w;
  lw.x = (f16)(v.x - (float)h.x); lw.y = (f16)(v.y - (float)h.y);
  lw.z = (f16)(v.z - (float)h.z); lw.w = (f16)(v.w - (float)h.w);
  *(f16x4*)(hi + l*4) = h;
  *(f16x4*)(lo + l*4) = lw;
  float s = v.x*v.x + v.y*v.y + v.z*v.z + v.w*v.w;
  #pragma unroll
  for (int o = 32; o; o >>= 1) s += __shfl_down(s, o, 64);
  if (l == 0) *nrm = s;
}

// ---------------- MFMA cost kernel, COMPACT targets: 128x128 tile, 64x64/wave ----------------
// All stores unconditional + coalesced (R4 pattern); tiles beyond nU[b] exit early.
__global__ __launch_bounds__(256) void cost_mfma_c_kernel(
    const f16* __restrict__ Ahi, const f16* __restrict__ Alo,
    const f16* __restrict__ Bhi, const f16* __restrict__ Blo,
    const float* __restrict__ x2, const float* __restrict__ y2,
    const int* __restrict__ nU,
    float* __restrict__ costC, float* __restrict__ costTC)
{
  __shared__ f16 sA[2][128*32];
  __shared__ f16 sB[2][128*32];
  int b = blockIdx.z;
  int q0 = blockIdx.y * 128, t0 = blockIdx.x * 128;
  if (t0 >= nU[b]) return;                  // compacted width ~nU ≈ T/2
  int tid = threadIdx.x, w = tid >> 6, l = tid & 63;
  int rq = (w >> 1) * 64, rt = (w & 1) * 64;
  int fr = l & 15, fg = l >> 4;
  const f16* pA[2] = { Ahi + ((size_t)b*QQ + q0) * DD, Alo + ((size_t)b*QQ + q0) * DD };
  const f16* pB[2] = { Bhi + ((size_t)b*TT + t0) * DD, Blo + ((size_t)b*TT + t0) * DD };
  f32x4 acc[4][4] = {};
  for (int k0 = 0; k0 < DD; k0 += 32) {
    __syncthreads();
#if __has_builtin(__builtin_amdgcn_global_load_lds)
    #pragma unroll
    for (int j = 0; j < 2; ++j) {
      int chunk = w*128 + j*64 + l;
      int row = chunk >> 2, kc = chunk & 3;
      size_t go = (size_t)row * DD + k0 + kc*8;
      int lb = (w*128 + j*64) * 8;
      #pragma unroll
      for (int h = 0; h < 2; ++h) {
        __builtin_amdgcn_global_load_lds(
            (const __attribute__((address_space(1))) void*)(pA[h] + go),
            (__attribute__((address_space(3))) void*)&sA[h][lb], 16, 0, 0);
        __builtin_amdgcn_global_load_lds(
            (const __attribute__((address_space(1))) void*)(pB[h] + go),
            (__attribute__((address_space(3))) void*)&sB[h][lb], 16, 0, 0);
      }
    }
#else
    #pragma unroll
    for (int j = 0; j < 2; ++j) {
      int chunk = w*128 + j*64 + l;
      int row = chunk >> 2, kc = chunk & 3;
      size_t go = (size_t)row * DD + k0 + kc*8;
      #pragma unroll
      for (int h = 0; h < 2; ++h) {
        *(f16x8*)&sA[h][chunk*8] = *(const f16x8*)(pA[h] + go);
        *(f16x8*)&sB[h][chunk*8] = *(const f16x8*)(pB[h] + go);
      }
    }
#endif
    __syncthreads();
    f16x8 ah[4], al[4], bh[4], bl[4];
    #pragma unroll
    for (int f = 0; f < 4; ++f) {
      int ao = (rq + f*16 + fr)*32 + fg*8;
      ah[f] = *(const f16x8*)&sA[0][ao];
      al[f] = *(const f16x8*)&sA[1][ao];
      int bo = (rt + f*16 + fr)*32 + fg*8;
      bh[f] = *(const f16x8*)&sB[0][bo];
      bl[f] = *(const f16x8*)&sB[1][bo];
    }
    #pragma unroll
    for (int fm = 0; fm < 4; ++fm)
      #pragma unroll
      for (int fn = 0; fn < 4; ++fn) {
        acc[fm][fn] = __builtin_amdgcn_mfma_f32_16x16x32_f16(ah[fm], bh[fn], acc[fm][fn], 0, 0, 0);
        acc[fm][fn] = __builtin_amdgcn_mfma_f32_16x16x32_f16(ah[fm], bl[fn], acc[fm][fn], 0, 0, 0);
        acc[fm][fn] = __builtin_amdgcn_mfma_f32_16x16x32_f16(al[fm], bh[fn], acc[fm][fn], 0, 0, 0);
      }
  }
  float xv[16];
  #pragma unroll
  for (int fm = 0; fm < 4; ++fm)
    #pragma unroll
    for (int r = 0; r < 4; ++r)
      xv[fm*4+r] = x2[(size_t)b*QQ + q0 + rq + fm*16 + fg*4 + r];
  float yv[4];
  #pragma unroll
  for (int fn = 0; fn < 4; ++fn)
    yv[fn] = y2[(size_t)b*TT + t0 + rt + fn*16 + fr];
  #pragma unroll
  for (int fm = 0; fm < 4; ++fm) {
    #pragma unroll
    for (int fn = 0; fn < 4; ++fn) {
      int t = t0 + rt + fn*16 + fr;      // compacted column index
      float cvr[4];
      #pragma unroll
      for (int r = 0; r < 4; ++r) {
        float c2 = xv[fm*4+r] + yv[fn] - 2.0f*acc[fm][fn][r];
        float craw = sqrtf(fmaxf(c2, 0.f));
        cvr[r] = craw;
        int q = q0 + rq + fm*16 + fg*4 + r;
        costC[((size_t)b*QQ + q)*TT + t] = craw;
      }
      float* dst = costTC + ((size_t)b*TT + t)*QQ + q0 + rq + fm*16 + fg*4;
      *(float4*)dst = make_float4(cvr[0], cvr[1], cvr[2], cvr[3]);
    }
  }
}

// ---------------- wave reductions ----------------
__device__ __forceinline__ float wave_max64(float v) {
  #pragma unroll
  for (int o = 1; o < 64; o <<= 1) v = fmaxf(v, __shfl_xor(v, o, 64));
  return v;
}
__device__ __forceinline__ float wave_sum64(float v) {
  #pragma unroll
  for (int o = 1; o < 64; o <<= 1) v += __shfl_xor(v, o, 64);
  return v;
}

// ================= COMPACT sweep kernels =================
__global__ __launch_bounds__(256) void u_c_kernel(
    const float* __restrict__ costC, const float* __restrict__ vC,
    const float* __restrict__ vf, const int* __restrict__ nU,
    float* __restrict__ u, int it0)
{
  int w = threadIdx.x >> 6, l = threadIdx.x & 63;
  int row = blockIdx.x * 8 + w * 2;
  int b = row >> 10;
  int n = nU[b];
  int nF = TT - n;
  const float4* c0 = (const float4*)(costC + (size_t)row * TT);
  const float4* c1 = c0 + TT/4;
  const float4* vb = (const float4*)(vC + (size_t)b * TT);
  float s0[16], s1[16], m0 = -3.0e38f, m1 = -3.0e38f;
  int iters = (n + 255) >> 8;
  #pragma unroll
  for (int i = 0; i < 4; ++i) {
    if (i < iters) {
      int jj = l + (i << 6);
      int j = jj << 2;
      float4 v4;
      if (it0) v4 = make_float4(0.f,0.f,0.f,0.f); else v4 = vb[jj];
      float4 a4 = c0[jj];
      float4 b4 = c1[jj];
      s0[4*i+0] = (j+0 < n) ? (v4.x - a4.x)*K2 : -3.0e38f;
      s0[4*i+1] = (j+1 < n) ? (v4.y - a4.y)*K2 : -3.0e38f;
      s0[4*i+2] = (j+2 < n) ? (v4.z - a4.z)*K2 : -3.0e38f;
      s0[4*i+3] = (j+3 < n) ? (v4.w - a4.w)*K2 : -3.0e38f;
      s1[4*i+0] = (j+0 < n) ? (v4.x - b4.x)*K2 : -3.0e38f;
      s1[4*i+1] = (j+1 < n) ? (v4.y - b4.y)*K2 : -3.0e38f;
      s1[4*i+2] = (j+2 < n) ? (v4.z - b4.z)*K2 : -3.0e38f;
      s1[4*i+3] = (j+3 < n) ? (v4.w - b4.w)*K2 : -3.0e38f;
      m0 = fmaxf(m0, fmaxf(fmaxf(s0[4*i+0], s0[4*i+1]), fmaxf(s0[4*i+2], s0[4*i+3])));
      m1 = fmaxf(m1, fmaxf(fmaxf(s1[4*i+0], s1[4*i+1]), fmaxf(s1[4*i+2], s1[4*i+3])));
    } else {
      #pragma unroll
      for (int k = 0; k < 4; ++k) { s0[4*i+k] = -3.0e38f; s1[4*i+k] = -3.0e38f; }
    }
  }
  float st = 0.f;
  if (nF > 0) {
    float vfb = it0 ? 0.f : vf[b];
    st = (vfb - FCONST) * K2;
    m0 = fmaxf(m0, st); m1 = fmaxf(m1, st);
  }
  m0 = wave_max64(m0); m1 = wave_max64(m1);
  float q0 = 0.f, q1 = 0.f;
  #pragma unroll
  for (int i = 0; i < 16; ++i) { q0 += fast_exp2(s0[i] - m0); q1 += fast_exp2(s1[i] - m1); }
  q0 = wave_sum64(q0); q1 = wave_sum64(q1);
  if (nF > 0) {
    q0 += (float)nF * fast_exp2(st - m0);
    q1 += (float)nF * fast_exp2(st - m1);
  }
  if (l == 0) {
    u[row]   = -EPSLN2 * (m0 + fast_log2(q0));
    u[row+1] = -EPSLN2 * (m1 + fast_log2(q1));
  }
}

__global__ __launch_bounds__(256) void v_c_kernel(
    const float* __restrict__ costTC,
    const float* __restrict__ filter, const int* __restrict__ cidx,
    const float* __restrict__ u, float* __restrict__ v,
    float* __restrict__ vC, float* __restrict__ vf)
{
  int w = threadIdx.x >> 6, l = threadIdx.x & 63;
  int row = blockIdx.x * 8 + w * 2;
  int b = row >> 10;
  const float4* ub = (const float4*)(u + (size_t)b * QQ);
  bool f0 = (filter[row]   <= 0.f);
  bool f1 = (filter[row+1] <= 0.f);
  int cj0 = cidx[row], cj1 = cidx[row+1];
  float4 uw[4];
  #pragma unroll
  for (int i = 0; i < 4; ++i) uw[i] = ub[l + (i << 6)];
  float s0[16], s1[16], m0 = -3.0e38f, m1 = -3.0e38f;
  if (f0) {
    #pragma unroll
    for (int i = 0; i < 4; ++i) {
      s0[4*i+0] = (uw[i].x - FCONST) * K2; s0[4*i+1] = (uw[i].y - FCONST) * K2;
      s0[4*i+2] = (uw[i].z - FCONST) * K2; s0[4*i+3] = (uw[i].w - FCONST) * K2;
    }
  } else {
    const float4* cr = (const float4*)(costTC + ((size_t)b*TT + cj0) * QQ);
    #pragma unroll
    for (int i = 0; i < 4; ++i) {
      float4 c4 = cr[l + (i << 6)];
      s0[4*i+0] = (uw[i].x - c4.x) * K2; s0[4*i+1] = (uw[i].y - c4.y) * K2;
      s0[4*i+2] = (uw[i].z - c4.z) * K2; s0[4*i+3] = (uw[i].w - c4.w) * K2;
    }
  }
  if (f1) {
    #pragma unroll
    for (int i = 0; i < 4; ++i) {
      s1[4*i+0] = (uw[i].x - FCONST) * K2; s1[4*i+1] = (uw[i].y - FCONST) * K2;
      s1[4*i+2] = (uw[i].z - FCONST) * K2; s1[4*i+3] = (uw[i].w - FCONST) * K2;
    }
  } else {
    const float4* cr = (const float4*)(costTC + ((size_t)b*TT + cj1) * QQ);
    #pragma unroll
    for (int i = 0; i < 4; ++i) {
      float4 c4 = cr[l + (i << 6)];
      s1[4*i+0] = (uw[i].x - c4.x) * K2; s1[4*i+1] = (uw[i].y - c4.y) * K2;
      s1[4*i+2] = (uw[i].z - c4.z) * K2; s1[4*i+3] = (uw[i].w - c4.w) * K2;
    }
  }
  #pragma unroll
  for (int i = 0; i < 16; ++i) { m0 = fmaxf(m0, s0[i]); m1 = fmaxf(m1, s1[i]); }
  m0 = wave_max64(m0); m1 = wave_max64(m1);
  float q0 = 0.f, q1 = 0.f;
  #pragma unroll
  for (int i = 0; i < 16; ++i) { q0 += fast_exp2(s0[i] - m0); q1 += fast_exp2(s1[i] - m1); }
  q0 = wave_sum64(q0); q1 = wave_sum64(q1);
  if (l == 0) {
    float val0 = -EPSLN2 * (m0 + fast_log2(q0));
    float val1 = -EPSLN2 * (m1 + fast_log2(q1));
    v[row]   = val0;
    v[row+1] = val1;
    if (f0) vf[b] = val0; else vC[(size_t)b*TT + cj0] = val0;
    if (f1) vf[b] = val1; else vC[(size_t)b*TT + cj1] = val1;
  }
}

__global__ __launch_bounds__(256) void p_c_kernel(
    const float* __restrict__ costC, const float* __restrict__ filter,
    const int* __restrict__ cidx, const int* __restrict__ nU,
    const int* __restrict__ f0i, const float* __restrict__ vf,
    const float* __restrict__ u, const float* __restrict__ v,
    float* __restrict__ P, float* __restrict__ idxOut)
{
  int w = threadIdx.x >> 6, l = threadIdx.x & 63;
  int row = blockIdx.x * 8 + w * 2;
  int b = row >> 10;
  int nF = TT - nU[b];
  float u0 = u[row], u1 = u[row+1];
  float pf0 = -1.f, pf1 = -1.f; int fidx = 0x7fffffff;
  if (nF > 0) {
    float vfb = vf[b];
    pf0 = fast_exp2((u0 + vfb - FCONST) * K2);
    pf1 = fast_exp2((u1 + vfb - FCONST) * K2);
    fidx = f0i[b];
  }
  const float* r0 = costC + (size_t)row * TT;
  const float* r1 = r0 + TT;
  float4* o0 = (float4*)(P + (size_t)row * TT);
  float4* o1 = o0 + TT/4;
  const float4* fb = (const float4*)(filter + (size_t)b * TT);
  const int4*   jb = (const int4*)(cidx + (size_t)b * TT);
  const float4* vv = (const float4*)(v + (size_t)b * TT);
  float bp0 = -1.f, bp1 = -1.f; int bt0 = 0x7ffffffe, bt1 = 0x7ffffffe;
  #pragma unroll
  for (int i = 0; i < 4; ++i) {
    int e = l + (i << 6);
    float4 f4 = fb[e];
    int4  j4 = jb[e];
    float4 v4 = vv[e];
    int tb = e << 2;
    float4 p0, p1;
#define PELEM(comp, jx, toff) \
    if (f4.comp > 0.f) { \
      float cA = r0[jx], cB = r1[jx]; \
      p0.comp = fast_exp2((u0 + v4.comp - cA) * K2); \
      p1.comp = fast_exp2((u1 + v4.comp - cB) * K2); \
      if (p0.comp > bp0) { bp0 = p0.comp; bt0 = tb + toff; } \
      if (p1.comp > bp1) { bp1 = p1.comp; bt1 = tb + toff; } \
    } else { p0.comp = pf0; p1.comp = pf1; }
    PELEM(x, j4.x, 0)
    PELEM(y, j4.y, 1)
    PELEM(z, j4.z, 2)
    PELEM(w, j4.w, 3)
#undef PELEM
    o0[e] = p0;
    o1[e] = p1;
  }
  #pragma unroll
  for (int o = 1; o < 64; o <<= 1) {
    float op = __shfl_xor(bp0, o, 64);
    int   ot = __shfl_xor(bt0, o, 64);
    if (op > bp0 || (op == bp0 && ot < bt0)) { bp0 = op; bt0 = ot; }
    op = __shfl_xor(bp1, o, 64);
    ot = __shfl_xor(bt1, o, 64);
    if (op > bp1 || (op == bp1 && ot < bt1)) { bp1 = op; bt1 = ot; }
  }
  if (l == 0) {
    if (pf0 > bp0 || (pf0 == bp0 && fidx < bt0)) bt0 = fidx;
    if (pf1 > bp1 || (pf1 == bp1 && fidx < bt1)) bt1 = fidx;
    idxOut[row]   = (float)bt0;
    idxOut[row+1] = (float)bt1;
  }
}

// ================= fp32 full fallback (small ws) =================
__global__ __launch_bounds__(64) void norms_kernel(
    const float* __restrict__ preds, const float* __restrict__ targets,
    float* __restrict__ x2, float* __restrict__ y2)
{
  int row = blockIdx.x;
  const float* src; float* dst;
  if (row < BB*QQ) { src = preds + (size_t)row * DD; dst = x2 + row; }
  else { int r = row - BB*QQ; src = targets + (size_t)r * DD; dst = y2 + r; }
  float4 v = ((const float4*)src)[threadIdx.x];
  float s = v.x*v.x + v.y*v.y + v.z*v.z + v.w*v.w;
  #pragma unroll
  for (int o = 32; o; o >>= 1) s += __shfl_down(s, o, 64);
  if (threadIdx.x == 0) *dst = s;
}

#define LDSTR 132
__global__ __launch_bounds__(256) void cost_fp32_kernel(
    const float* __restrict__ preds, const float* __restrict__ targets,
    const float* __restrict__ x2, const float* __restrict__ y2,
    const float* __restrict__ filter,
    float* __restrict__ cost)
{
  __shared__ float As[16*LDSTR];
  __shared__ float Bs[16*LDSTR];
  int b  = blockIdx.z;
  int q0 = blockIdx.y * 128;
  int t0 = blockIdx.x * 128;
  const float* Ab = preds   + ((size_t)b*QQ + q0) * DD;
  const float* Bb = targets + ((size_t)b*TT + t0) * DD;
  int tid = threadIdx.x;
  int srow = tid >> 2, sq = (tid & 3) << 2;
  int w = tid >> 6, l = tid & 63;
  int rq = ((w >> 1) << 6) + ((l >> 3) << 3);
  int rt = ((w & 1) << 6) + ((l & 7) << 3);
  float acc[8][8] = {};
  for (int k0 = 0; k0 < DD; k0 += 16) {
    float4 a0 = *(const float4*)(Ab + (size_t)srow*DD + k0 + sq);
    float4 a1 = *(const float4*)(Ab + (size_t)(srow+64)*DD + k0 + sq);
    float4 b0 = *(const float4*)(Bb + (size_t)srow*DD + k0 + sq);
    float4 b1 = *(const float4*)(Bb + (size_t)(srow+64)*DD + k0 + sq);
    __syncthreads();
    As[(sq+0)*LDSTR + srow] = a0.x; As[(sq+1)*LDSTR + srow] = a0.y;
    As[(sq+2)*LDSTR + srow] = a0.z; As[(sq+3)*LDSTR + srow] = a0.w;
    As[(sq+0)*LDSTR + srow+64] = a1.x; As[(sq+1)*LDSTR + srow+64] = a1.y;
    As[(sq+2)*LDSTR + srow+64] = a1.z; As[(sq+3)*LDSTR + srow+64] = a1.w;
    Bs[(sq+0)*LDSTR + srow] = b0.x; Bs[(sq+1)*LDSTR + srow] = b0.y;
    Bs[(sq+2)*LDSTR + srow] = b0.z; Bs[(sq+3)*LDSTR + srow] = b0.w;
    Bs[(sq+0)*LDSTR + srow+64] = b1.x; Bs[(sq+1)*LDSTR + srow+64] = b1.y;
    Bs[(sq+2)*LDSTR + srow+64] = b1.z; Bs[(sq+3)*LDSTR + srow+64] = b1.w;
    __syncthreads();
    #pragma unroll
    for (int k = 0; k < 16; ++k) {
      float4 af0 = *(const float4*)&As[k*LDSTR + rq];
      float4 af1 = *(const float4*)&As[k*LDSTR + rq + 4];
      float4 bf0 = *(const float4*)&Bs[k*LDSTR + rt];
      float4 bf1 = *(const float4*)&Bs[k*LDSTR + rt + 4];
      float aa[8] = {af0.x,af0.y,af0.z,af0.w,af1.x,af1.y,af1.z,af1.w};
      float bb[8] = {bf0.x,bf0.y,bf0.z,bf0.w,bf1.x,bf1.y,bf1.z,bf1.w};
      #pragma unroll
      for (int i = 0; i < 8; ++i)
        #pragma unroll
        for (int j = 0; j < 8; ++j)
          acc[i][j] = fmaf(aa[i], bb[j], acc[i][j]);
    }
  }
  float xq[8], yt[8], fvv[8];
  #pragma unroll
  for (int i = 0; i < 8; ++i) xq[i] = x2[(size_t)b*QQ + q0 + rq + i];
  #pragma unroll
  for (int j = 0; j < 8; ++j) {
    yt[j] = y2[(size_t)b*TT + t0 + rt + j];
    fvv[j] = filter[(size_t)b*TT + t0 + rt + j];
  }
  float cv[8][8];
  #pragma unroll
  for (int i = 0; i < 8; ++i)
    #pragma unroll
    for (int j = 0; j < 8; ++j) {
      float c2 = xq[i] + yt[j] - 2.f*acc[i][j];
      float c = sqrtf(fmaxf(c2, 0.f));
      if (fvv[j] <= 0.f) c = FCONST;
      cv[i][j] = c;
    }
  #pragma unroll
  for (int i = 0; i < 8; ++i) {
    float* dst = cost + ((size_t)b*QQ + q0 + rq + i) * TT + t0 + rt;
    *(float4*)dst       = make_float4(cv[i][0], cv[i][1], cv[i][2], cv[i][3]);
    *(float4*)(dst + 4) = make_float4(cv[i][4], cv[i][5], cv[i][6], cv[i][7]);
  }
}

__global__ __launch_bounds__(256) void u_kernel(
    const float* __restrict__ cost, const float* __restrict__ v, float* __restrict__ u, int it0)
{
  int w = threadIdx.x >> 6, l = threadIdx.x & 63;
  int row = blockIdx.x * 8 + w * 2;
  int b = row >> 10;
  const float4* c0 = (const float4*)(cost + (size_t)row * TT);
  const float4* c1 = c0 + TT/4;
  const float4* vb = (const float4*)(v + (size_t)b * TT);
  float s0[16], s1[16], m0 = -3.0e38f, m1 = -3.0e38f;
  #pragma unroll
  for (int i = 0; i < 4; ++i) {
    float4 v4;
    if (it0) v4 = make_float4(0.f, 0.f, 0.f, 0.f);
    else     v4 = vb[l + (i << 6)];
    float4 a4 = c0[l + (i << 6)];
    float4 b4 = c1[l + (i << 6)];
    s0[4*i+0] = (v4.x - a4.x) * K2; s0[4*i+1] = (v4.y - a4.y) * K2;
    s0[4*i+2] = (v4.z - a4.z) * K2; s0[4*i+3] = (v4.w - a4.w) * K2;
    s1[4*i+0] = (v4.x - b4.x) * K2; s1[4*i+1] = (v4.y - b4.y) * K2;
    s1[4*i+2] = (v4.z - b4.z) * K2; s1[4*i+3] = (v4.w - b4.w) * K2;
    m0 = fmaxf(m0, fmaxf(fmaxf(s0[4*i+0], s0[4*i+1]), fmaxf(s0[4*i+2], s0[4*i+3])));
    m1 = fmaxf(m1, fmaxf(fmaxf(s1[4*i+0], s1[4*i+1]), fmaxf(s1[4*i+2], s1[4*i+3])));
  }
  m0 = wave_max64(m0); m1 = wave_max64(m1);
  float q0 = 0.f, q1 = 0.f;
  #pragma unroll
  for (int i = 0; i < 16; ++i) { q0 += fast_exp2(s0[i] - m0); q1 += fast_exp2(s1[i] - m1); }
  q0 = wave_sum64(q0); q1 = wave_sum64(q1);
  if (l == 0) {
    u[row]   = -EPSLN2 * (m0 + fast_log2(q0));
    u[row+1] = -EPSLN2 * (m1 + fast_log2(q1));
  }
}

__global__ __launch_bounds__(256) void v_kernel(
    const float* __restrict__ cost,
    const float* __restrict__ filter, const float* __restrict__ u, float* __restrict__ v)
{
  int w = threadIdx.x >> 6, l = threadIdx.x & 63;
  int row = blockIdx.x * 8 + w * 2;
  int b = row >> 10, t = row & 1023;
  const float4* ub = (const float4*)(u + (size_t)b * QQ);
  bool f0 = (filter[row]   <= 0.f);
  bool f1 = (filter[row+1] <= 0.f);
  float4 uw[4];
  #pragma unroll
  for (int i = 0; i < 4; ++i) uw[i] = ub[l + (i << 6)];
  float s0[16], s1[16], m0 = -3.0e38f, m1 = -3.0e38f;
  const float* cr = cost + (size_t)b*QQ*TT + t;
  #pragma unroll
  for (int i = 0; i < 4; ++i) {
    int q = (l + (i << 6)) << 2;
    if (f0) {
      s0[4*i+0] = (uw[i].x - FCONST) * K2; s0[4*i+1] = (uw[i].y - FCONST) * K2;
      s0[4*i+2] = (uw[i].z - FCONST) * K2; s0[4*i+3] = (uw[i].w - FCONST) * K2;
    } else {
      s0[4*i+0] = (uw[i].x - cr[(size_t)(q+0)*TT]) * K2;
      s0[4*i+1] = (uw[i].y - cr[(size_t)(q+1)*TT]) * K2;
      s0[4*i+2] = (uw[i].z - cr[(size_t)(q+2)*TT]) * K2;
      s0[4*i+3] = (uw[i].w - cr[(size_t)(q+3)*TT]) * K2;
    }
    if (f1) {
      s1[4*i+0] = (uw[i].x - FCONST) * K2; s1[4*i+1] = (uw[i].y - FCONST) * K2;
      s1[4*i+2] = (uw[i].z - FCONST) * K2; s1[4*i+3] = (uw[i].w - FCONST) * K2;
    } else {
      s1[4*i+0] = (uw[i].x - cr[(size_t)(q+0)*TT + 1]) * K2;
      s1[4*i+1] = (uw[i].y - cr[(size_t)(q+1)*TT + 1]) * K2;
      s1[4*i+2] = (uw[i].z - cr[(size_t)(q+2)*TT + 1]) * K2;
      s1[4*i+3] = (uw[i].w - cr[(size_t)(q+3)*TT + 1]) * K2;
    }
  }
  #pragma unroll
  for (int i = 0; i < 16; ++i) { m0 = fmaxf(m0, s0[i]); m1 = fmaxf(m1, s1[i]); }
  m0 = wave_max64(m0); m1 = wave_max64(m1);
  float q0 = 0.f, q1 = 0.f;
  #pragma unroll
  for (int i = 0; i < 16; ++i) { q0 += fast_exp2(s0[i] - m0); q1 += fast_exp2(s1[i] - m1); }
  q0 = wave_sum64(q0); q1 = wave_sum64(q1);
  if (l == 0) {
    v[row]   = -EPSLN2 * (m0 + fast_log2(q0));
    v[row+1] = -EPSLN2 * (m1 + fast_log2(q1));
  }
}

__global__ __launch_bounds__(256) void p_kernel(
    float* __restrict__ P, const float* __restrict__ u, const float* __restrict__ v,
    float* __restrict__ idxOut)
{
  int w = threadIdx.x >> 6, l = threadIdx.x & 63;
  int row = blockIdx.x * 8 + w * 2;
  int b = row >> 10;
  float4* c0 = (float4*)(P + (size_t)row * TT);
  float4* c1 = c0 + TT/4;
  const float4* vb = (const float4*)(v + (size_t)b * TT);
  float u0 = u[row], u1 = u[row+1];
  float bp0 = -1.f, bp1 = -1.f; int bt0 = 0, bt1 = 0;
  #pragma unroll
  for (int i = 0; i < 4; ++i) {
    float4 v4 = vb[l + (i << 6)];
    float4 a4 = c0[l + (i << 6)];
    float4 b4 = c1[l + (i << 6)];
    int t0 = (l + (i << 6)) << 2;
    float4 p0, p1;
    p0.x = fast_exp2((u0 + v4.x - a4.x) * K2);
    p0.y = fast_exp2((u0 + v4.y - a4.y) * K2);
    p0.z = fast_exp2((u0 + v4.z - a4.z) * K2);
    p0.w = fast_exp2((u0 + v4.w - a4.w) * K2);
    p1.x = fast_exp2((u1 + v4.x - b4.x) * K2);
    p1.y = fast_exp2((u1 + v4.y - b4.y) * K2);
    p1.z = fast_exp2((u1 + v4.z - b4.z) * K2);
    p1.w = fast_exp2((u1 + v4.w - b4.w) * K2);
    if (p0.x > bp0) { bp0 = p0.x; bt0 = t0 + 0; }
    if (p0.y > bp0) { bp0 = p0.y; bt0 = t0 + 1; }
    if (p0.z > bp0) { bp0 = p0.z; bt0 = t0 + 2; }
    if (p0.w > bp0) { bp0 = p0.w; bt0 = t0 + 3; }
    if (p1.x > bp1) { bp1 = p1.x; bt1 = t0 + 0; }
    if (p1.y > bp1) { bp1 = p1.y; bt1 = t0 + 1; }
    if (p1.z > bp1) { bp1 = p1.z; bt1 = t0 + 2; }
    if (p1.w > bp1) { bp1 = p1.w; bt1 = t0 + 3; }
    c0[l + (i << 6)] = p0;
    c1[l + (i << 6)] = p1;
  }
  #pragma unroll
  for (int o = 1; o < 64; o <<= 1) {
    float op = __shfl_xor(bp0, o, 64);
    int   ot = __shfl_xor(bt0, o, 64);
    if (op > bp0 || (op == bp0 && ot < bt0)) { bp0 = op; bt0 = ot; }
    op = __shfl_xor(bp1, o, 64);
    ot = __shfl_xor(bt1, o, 64);
    if (op > bp1 || (op == bp1 && ot < bt1)) { bp1 = op; bt1 = ot; }
  }
  if (l == 0) { idxOut[row] = (float)bt0; idxOut[row+1] = (float)bt1; }
}

extern "C" void kernel_launch(void* const* d_in, const int* in_sizes, int n_in,
                              void* d_out, int out_size, void* d_ws, size_t ws_size,
                              hipStream_t stream) {
  const float* preds   = (const float*)d_in[0];
  const float* targets = (const float*)d_in[1];
  const float* filter  = (const float*)d_in[2];
  float* out = (float*)d_out;
  float* idxOut = out;
  float* P = out + (size_t)BB*QQ;

  const size_t F16A   = (size_t)BB*QQ*DD;
  const size_t f16tot = 4 * F16A * sizeof(f16);          // 33.55 MB
  const size_t SMALL  = (size_t)1 << 19;                 // 512 KB small arrays
  const size_t CB     = (size_t)BB * QQ * TT * sizeof(float);  // 67.1 MB

  char* ws = (char*)d_ws;
  int useC = ws_size >= f16tot + SMALL + 2*CB;           // compact MFMA path
  f16 *Ahi = (f16*)ws, *Alo = Ahi + F16A, *Bhi = Alo + F16A, *Blo = Bhi + F16A;
  char* base = ws + (useC ? f16tot : 0);
  float* x2 = (float*)base;
  float* y2 = x2 + 16384;
  float* u  = y2 + 16384;
  float* v  = u + 16384;
  float* vC = v + 16384;
  float* vf = vC + 16384;          // 16 floats
  int* nU   = (int*)(vf + 64);
  int* f0i  = nU + 64;
  int* cidx = f0i + 64;            // 16384 ints
  float* costTC = (float*)(base + SMALL);
  float* costC  = (float*)(base + SMALL + CB);

  int blks = BB*QQ/8;
  if (useC) {
    scan_kernel<<<BB, 256, 0, stream>>>(filter, nU, f0i, cidx);
    cvt_c_kernel<<<BB*(QQ+TT)/4, 256, 0, stream>>>(preds, targets, filter, cidx,
                                                   Ahi, Alo, Bhi, Blo, x2, y2);
    dim3 cg_(TT/128, QQ/128, BB);
    cost_mfma_c_kernel<<<cg_, 256, 0, stream>>>(Ahi, Alo, Bhi, Blo, x2, y2, nU, costC, costTC);
    for (int it = 0; it < SINK_ITERS; ++it) {
      u_c_kernel<<<blks, 256, 0, stream>>>(costC, vC, vf, nU, u, it == 0 ? 1 : 0);
      v_c_kernel<<<blks, 256, 0, stream>>>(costTC, filter, cidx, u, v, vC, vf);
    }
    p_c_kernel<<<blks, 256, 0, stream>>>(costC, filter, cidx, nU, f0i, vf, u, v, P, idxOut);
  } else {
    // minimal fallback: fp32 cost into P, strided v reads (L3-resident)
    norms_kernel<<<BB*(QQ+TT), 64, 0, stream>>>(preds, targets, x2, y2);
    dim3 cg_(TT/128, QQ/128, BB);
    cost_fp32_kernel<<<cg_, 256, 0, stream>>>(preds, targets, x2, y2, filter, P);
    for (int it = 0; it < SINK_ITERS; ++it) {
      u_kernel<<<blks, 256, 0, stream>>>(P, v, u, it == 0 ? 1 : 0);
      v_kernel<<<blks, 256, 0, stream>>>(P, filter, u, v);
    }
    p_kernel<<<blks, 256, 0, stream>>>(P, u, v, idxOut);
  }
}